// Round 3
// baseline (584.689 us; speedup 1.0000x reference)
//
#include <hip/hip_runtime.h>
#include <cstdint>
#include <cstddef>

// MorphoGPT predictor loss, fully fused on-device. v3.
// stats kernels: emb cols in registers (AGPR), 2 row-tiles ILP, pure exp
// epilogue (targets + smooth-sum handled out-of-loop / in-loop sum),
// block-LDS-reduced partials. Colsum machinery removed (smooth term = V*logZ
// - sum(logits), accumulated in-kernel).

typedef __attribute__((ext_vector_type(8))) __bf16 bf16x8;
typedef __attribute__((ext_vector_type(4))) float f32x4;
typedef __attribute__((ext_vector_type(4))) unsigned short u16x4;
typedef __attribute__((ext_vector_type(2))) unsigned short u16x2;

namespace {
constexpr int S_LEN   = 448;
constexpr int N_SEQ   = 8;
constexpr int D_MODEL = 768;
constexpr int TPAD    = 3584;      // padded token rows (T = 3576)
constexpr int VS = 50000, VP = 200, VM = 400, VA = 360;
constexpr int DS_STEM = 256, DS_POS = 128, DS_MORPH = 128, DS_AFF = 128;
constexpr int VS_PAD = 50176;      // 196 * 256
constexpr int VP_PAD = 256;
constexpr int VM_PAD = 512;
constexpr int VA_PAD = 512;
constexpr int NVB_S = VS_PAD / 256; // 196: one partial per 256-col block
constexpr int NVB_P = 1;
constexpr int NVB_M = 2;
constexpr int ITERS = 14;           // rows per block = ITERS*32 = 448; 8 x-blocks
}

__device__ __forceinline__ unsigned short f2bf(float f) {
  unsigned int u = __float_as_uint(f);
  unsigned int r = (u + 0x7FFFu + ((u >> 16) & 1u)) >> 16;  // RNE
  return (unsigned short)r;
}
__device__ __forceinline__ float bf2f(unsigned short u) {
  return __uint_as_float(((unsigned int)u) << 16);
}

// ---------------- prep kernels ----------------

// x[t,d] = bf16(tr_hidden[s, n, d]); also pre-gathers targets and affix rows.
__global__ __launch_bounds__(256) void gather_x_kernel(
    const float* __restrict__ tr, const int* __restrict__ hsel,
    const int* __restrict__ tsel, const int* __restrict__ asel,
    const int* __restrict__ stems, const int* __restrict__ postags,
    const int* __restrict__ morphs,
    unsigned short* __restrict__ x, int* __restrict__ tgtS, int* __restrict__ tgtP,
    int* __restrict__ tgtM, int* __restrict__ arow, int T, int Ta) {
  const size_t e = (size_t)blockIdx.x * 256 + threadIdx.x;  // e < TPAD*768 exact
  const int t = (int)(e / D_MODEL);
  const int d = (int)(e % D_MODEL);
  float v = 0.f;
  if (t < T) {
    int idx = hsel[t];
    int n = idx / S_LEN, s = idx % S_LEN;
    v = tr[((size_t)s * N_SEQ + n) * D_MODEL + d];
  }
  x[e] = f2bf(v);
  if (e < (size_t)T) {
    int tt = tsel[e];
    tgtS[e] = stems[tt]; tgtP[e] = postags[tt]; tgtM[e] = morphs[tt];
  }
  if (e < (size_t)Ta) arow[e] = tsel[asel[e]];
}

// All four W transposes fused: Wt[n,k] = bf16(W[k,n]).
__global__ __launch_bounds__(256) void transpose_all_kernel(
    const float* __restrict__ sW, const float* __restrict__ pW,
    const float* __restrict__ mW, const float* __restrict__ aW,
    unsigned short* __restrict__ wtS, unsigned short* __restrict__ wtP,
    unsigned short* __restrict__ wtM, unsigned short* __restrict__ wtA) {
  const int e = blockIdx.x * 256 + threadIdx.x;  // < 491520 exact
  const float* W; unsigned short* Wt; int DS; int local;
  if (e < 196608)      { W = sW; Wt = wtS; DS = 256; local = e; }
  else if (e < 294912) { W = pW; Wt = wtP; DS = 128; local = e - 196608; }
  else if (e < 393216) { W = mW; Wt = wtM; DS = 128; local = e - 294912; }
  else                 { W = aW; Wt = wtA; DS = 128; local = e - 393216; }
  const int n = local / D_MODEL, k = local % D_MODEL;
  Wt[local] = f2bf(W[(size_t)k * DS + n]);
}

// All four emb casts fused, float4 in / ushort4 out, zero padding rows.
__global__ __launch_bounds__(256) void conv_emb_all_kernel(
    const float* __restrict__ sE, const float* __restrict__ pE,
    const float* __restrict__ mE, const float* __restrict__ aE,
    unsigned short* __restrict__ dS, unsigned short* __restrict__ dP,
    unsigned short* __restrict__ dM, unsigned short* __restrict__ dA) {
  const size_t q = ((size_t)blockIdx.x * 256 + threadIdx.x) * 4;
  // regions (padded elems): stem 12845056, P 32768, M 65536, A 65536
  const float* src; unsigned short* dst; size_t local, real;
  if (q < 12845056)            { src = sE; dst = dS; local = q;            real = 12800000; }
  else if (q < 12877824)       { src = pE; dst = dP; local = q - 12845056; real = 25600; }
  else if (q < 12943360)       { src = mE; dst = dM; local = q - 12877824; real = 51200; }
  else                         { src = aE; dst = dA; local = q - 12943360; real = 46080; }
  float4 v = make_float4(0.f, 0.f, 0.f, 0.f);
  if (local < real) v = *(const float4*)(src + local);
  u16x4 o = { f2bf(v.x), f2bf(v.y), f2bf(v.z), f2bf(v.w) };
  *(u16x4*)(dst + local) = o;
}

// ---------------- head transform: h = LN(gelu(x @ W + b)) * g + beta ----------------
template <int NT>
__device__ __forceinline__ void head_body(
    const unsigned short* __restrict__ x, const unsigned short* __restrict__ Wt,
    const float* __restrict__ bvec, const float* __restrict__ gvec,
    const float* __restrict__ betav, unsigned short* __restrict__ hout) {
  constexpr int DS = NT * 16;
  const int lane = threadIdx.x & 63;
  const int wave = threadIdx.x >> 6;           // 0..1 (128-thread block)
  const int row0 = blockIdx.x * 32 + wave * 16;
  const int lrow = lane & 15;
  const int lk8  = (lane >> 4) * 8;

  f32x4 acc[NT];
#pragma unroll
  for (int nt = 0; nt < NT; ++nt) acc[nt] = f32x4{0.f, 0.f, 0.f, 0.f};

  const unsigned short* xrow = x + (size_t)(row0 + lrow) * D_MODEL + lk8;
#pragma unroll
  for (int ks = 0; ks < 24; ++ks) {  // K = 768 = 24 * 32
    bf16x8 a = *(const bf16x8*)(xrow + ks * 32);
#pragma unroll
    for (int nt = 0; nt < NT; ++nt) {
      bf16x8 b = *(const bf16x8*)(Wt + (size_t)(nt * 16 + lrow) * D_MODEL + ks * 32 + lk8);
      acc[nt] = __builtin_amdgcn_mfma_f32_16x16x32_bf16(a, b, acc[nt], 0, 0, 0);
    }
  }

  float bb[NT], gg[NT], be[NT];
#pragma unroll
  for (int nt = 0; nt < NT; ++nt) {
    int c = nt * 16 + lrow;
    bb[nt] = bvec[c]; gg[nt] = gvec[c]; be[nt] = betav[c];
  }
#pragma unroll
  for (int r = 0; r < 4; ++r) {
    const int row = row0 + (lane >> 4) * 4 + r;
    float vals[NT];
    float s = 0.f, s2 = 0.f;
#pragma unroll
    for (int nt = 0; nt < NT; ++nt) {
      float v = acc[nt][r] + bb[nt];
      v = 0.5f * v * (1.f + erff(v * 0.70710678118654752f));  // exact erf-gelu
      vals[nt] = v; s += v; s2 += v * v;
    }
    s  += __shfl_xor(s, 1);  s  += __shfl_xor(s, 2);  s  += __shfl_xor(s, 4);  s  += __shfl_xor(s, 8);
    s2 += __shfl_xor(s2, 1); s2 += __shfl_xor(s2, 2); s2 += __shfl_xor(s2, 4); s2 += __shfl_xor(s2, 8);
    const float mean = s * (1.f / DS);
    const float var  = s2 * (1.f / DS) - mean * mean;
    const float rstd = rsqrtf(var + 1e-12f);
#pragma unroll
    for (int nt = 0; nt < NT; ++nt) {
      float o = (vals[nt] - mean) * rstd * gg[nt] + be[nt];
      hout[(size_t)row * DS + nt * 16 + lrow] = f2bf(o);
    }
  }
}

__global__ __launch_bounds__(128, 2) void head_stem_kernel(
    const unsigned short* __restrict__ x, const unsigned short* __restrict__ Wt,
    const float* __restrict__ bvec, const float* __restrict__ gvec,
    const float* __restrict__ betav, unsigned short* __restrict__ hout) {
  head_body<16>(x, Wt, bvec, gvec, betav, hout);
}

__global__ __launch_bounds__(128, 2) void head_pma_kernel(
    const unsigned short* __restrict__ x,
    const unsigned short* __restrict__ wtP, const float* __restrict__ pb,
    const float* __restrict__ pg, const float* __restrict__ pbe, unsigned short* __restrict__ hP,
    const unsigned short* __restrict__ wtM, const float* __restrict__ mb,
    const float* __restrict__ mg, const float* __restrict__ mbe, unsigned short* __restrict__ hM,
    const unsigned short* __restrict__ wtA, const float* __restrict__ ab,
    const float* __restrict__ ag, const float* __restrict__ abe, unsigned short* __restrict__ hA) {
  const unsigned short* Wt; const float *bv, *gv, *be; unsigned short* ho;
  if (blockIdx.y == 0)      { Wt = wtP; bv = pb; gv = pg; be = pbe; ho = hP; }
  else if (blockIdx.y == 1) { Wt = wtM; bv = mb; gv = mg; be = mbe; ho = hM; }
  else                      { Wt = wtA; bv = ab; gv = ag; be = abe; ho = hA; }
  head_body<8>(x, Wt, bv, gv, be, ho);
}

// ---------------- streaming softmax stats ----------------
// Wave owns 64 vocab cols (registers/AGPR), streams rows in 32-row tiles.
// Per row emits sum(exp(logit)) and sum(logit) (smooth term), block-reduced
// across the 4 waves (256 cols) into psum/psum2[row][blockIdx.y].
template <int KS>  // DK = KS*32
__global__ __launch_bounds__(256, 2) void stats2_kernel(
    const unsigned short* __restrict__ h, const unsigned short* __restrict__ emb,
    const float* __restrict__ bias, float* __restrict__ psum,
    float* __restrict__ psum2, int V, int NVB) {
  constexpr int DK = KS * 32;
  const int lane = threadIdx.x & 63;
  const int wave = threadIdx.x >> 6;
  const int colbase = blockIdx.y * 256 + wave * 64;
  const int row0 = blockIdx.x * (ITERS * 32);
  const int lrow = lane & 15;
  const int hi   = lane >> 4;
  const int lk8  = hi * 8;

  __shared__ float lds_e[4][32];
  __shared__ float lds_s[4][32];

  bf16x8 bfr[KS][4];
  float bv[4];
  bool mk[4];
#pragma unroll
  for (int nt = 0; nt < 4; ++nt) {
    int col = colbase + nt * 16 + lrow;
#pragma unroll
    for (int ks = 0; ks < KS; ++ks)
      bfr[ks][nt] = *(const bf16x8*)(emb + (size_t)col * DK + ks * 32 + lk8);
    mk[nt] = (col < V);
    bv[nt] = mk[nt] ? bias[col] : 0.f;
  }

  for (int it = 0; it < ITERS; ++it) {
    const int rb = row0 + it * 32;
    f32x4 acc[2][4];
#pragma unroll
    for (int rt = 0; rt < 2; ++rt)
#pragma unroll
      for (int nt = 0; nt < 4; ++nt) acc[rt][nt] = f32x4{0.f, 0.f, 0.f, 0.f};

    const unsigned short* hrow = h + (size_t)(rb + lrow) * DK + lk8;
#pragma unroll
    for (int ks = 0; ks < KS; ++ks) {
#pragma unroll
      for (int rt = 0; rt < 2; ++rt) {
        bf16x8 a = *(const bf16x8*)(hrow + (size_t)rt * 16 * DK + ks * 32);
#pragma unroll
        for (int nt = 0; nt < 4; ++nt)
          acc[rt][nt] = __builtin_amdgcn_mfma_f32_16x16x32_bf16(a, bfr[ks][nt], acc[rt][nt], 0, 0, 0);
      }
    }

#pragma unroll
    for (int rt = 0; rt < 2; ++rt)
#pragma unroll
      for (int r = 0; r < 4; ++r) {
        float e = 0.f, s = 0.f;
#pragma unroll
        for (int nt = 0; nt < 4; ++nt) {
          float v = acc[rt][nt][r] + bv[nt];
          float ev = __expf(v);  // |logit| small (LN rows x 0.02-scale emb): max-free safe
          e += mk[nt] ? ev : 0.f;
          s += mk[nt] ? v : 0.f;
        }
        e += __shfl_xor(e, 1); e += __shfl_xor(e, 2); e += __shfl_xor(e, 4); e += __shfl_xor(e, 8);
        s += __shfl_xor(s, 1); s += __shfl_xor(s, 2); s += __shfl_xor(s, 4); s += __shfl_xor(s, 8);
        if (lrow == 0) {
          lds_e[wave][rt * 16 + hi * 4 + r] = e;
          lds_s[wave][rt * 16 + hi * 4 + r] = s;
        }
      }
    __syncthreads();
    if (threadIdx.x < 32) {
      const int rr = threadIdx.x;
      float e = lds_e[0][rr] + lds_e[1][rr] + lds_e[2][rr] + lds_e[3][rr];
      float s = lds_s[0][rr] + lds_s[1][rr] + lds_s[2][rr] + lds_s[3][rr];
      const int row = rb + rr;
      psum[(size_t)row * NVB + blockIdx.y]  = e;
      psum2[(size_t)row * NVB + blockIdx.y] = s;
    }
    __syncthreads();
  }
}

// ---------------- target logits: tgtlog[hd,t] = h[t]·emb[tgt[t]] + bias[tgt] ----------------
__global__ __launch_bounds__(256) void tgtlog_kernel(
    const unsigned short* __restrict__ hS, const unsigned short* __restrict__ embS,
    const float* __restrict__ bS, const int* __restrict__ tgtS,
    const unsigned short* __restrict__ hP, const unsigned short* __restrict__ embP,
    const float* __restrict__ bP, const int* __restrict__ tgtP,
    const unsigned short* __restrict__ hM, const unsigned short* __restrict__ embM,
    const float* __restrict__ bM, const int* __restrict__ tgtM,
    float* __restrict__ tgtlog, int T) {
  const int lane = threadIdx.x & 63;
  const int wave = threadIdx.x >> 6;
  const int t = blockIdx.x * 4 + wave;
  const int hd = blockIdx.y;
  if (t >= T) return;
  float dot = 0.f; float bvv = 0.f;
  if (hd == 0) {
    const int tg = tgtS[t];
    u16x4 hv = *(const u16x4*)(hS + (size_t)t * 256 + lane * 4);
    u16x4 ev = *(const u16x4*)(embS + (size_t)tg * 256 + lane * 4);
    dot = bf2f(hv[0]) * bf2f(ev[0]) + bf2f(hv[1]) * bf2f(ev[1]) +
          bf2f(hv[2]) * bf2f(ev[2]) + bf2f(hv[3]) * bf2f(ev[3]);
    bvv = bS[tg];
  } else if (hd == 1) {
    const int tg = tgtP[t];
    u16x2 hv = *(const u16x2*)(hP + (size_t)t * 128 + lane * 2);
    u16x2 ev = *(const u16x2*)(embP + (size_t)tg * 128 + lane * 2);
    dot = bf2f(hv[0]) * bf2f(ev[0]) + bf2f(hv[1]) * bf2f(ev[1]);
    bvv = bP[tg];
  } else {
    const int tg = tgtM[t];
    u16x2 hv = *(const u16x2*)(hM + (size_t)t * 128 + lane * 2);
    u16x2 ev = *(const u16x2*)(embM + (size_t)tg * 128 + lane * 2);
    dot = bf2f(hv[0]) * bf2f(ev[0]) + bf2f(hv[1]) * bf2f(ev[1]);
    bvv = bM[tg];
  }
#pragma unroll
  for (int m = 1; m < 64; m <<= 1) dot += __shfl_xor(dot, m);
  if (lane == 0) tgtlog[hd * TPAD + t] = dot + bvv;
}

// ---------------- affix head: BCE-with-logits ----------------
__global__ __launch_bounds__(256, 2) void aff_bce_kernel(
    const unsigned short* __restrict__ h, const unsigned short* __restrict__ emb,
    const float* __restrict__ bias, const int* __restrict__ asel,
    const int* __restrict__ arow, const float* __restrict__ aprob,
    float* __restrict__ partial, int Ta) {
  const int lane = threadIdx.x & 63;
  const int wave = threadIdx.x >> 6;
  const int colbase = blockIdx.y * 256 + wave * 64;
  const int lrow = lane & 15;
  const int lk8  = (lane >> 4) * 8;

  bf16x8 bfr[4][4];
  float bv[4];
  bool mk[4];
#pragma unroll
  for (int nt = 0; nt < 4; ++nt) {
    int col = colbase + nt * 16 + lrow;
#pragma unroll
    for (int ks = 0; ks < 4; ++ks)
      bfr[ks][nt] = *(const bf16x8*)(emb + (size_t)col * DS_AFF + ks * 32 + lk8);
    mk[nt] = (col < VA);
    bv[nt] = mk[nt] ? bias[col] : 0.f;
  }

  float lsum = 0.f;
  for (int it = 0; it < 4; ++it) {
    const int rb = blockIdx.x * 64 + it * 16;
    const int ia = rb + lrow;
    const int srow = (ia < Ta) ? asel[ia] : 0;  // gather h rows via affix_sel
    f32x4 acc[4];
#pragma unroll
    for (int nt = 0; nt < 4; ++nt) acc[nt] = f32x4{0.f, 0.f, 0.f, 0.f};
    const unsigned short* hrow = h + (size_t)srow * DS_AFF + lk8;
#pragma unroll
    for (int ks = 0; ks < 4; ++ks) {
      bf16x8 a = *(const bf16x8*)(hrow + ks * 32);
#pragma unroll
      for (int nt = 0; nt < 4; ++nt)
        acc[nt] = __builtin_amdgcn_mfma_f32_16x16x32_bf16(a, bfr[ks][nt], acc[nt], 0, 0, 0);
    }
#pragma unroll
    for (int r = 0; r < 4; ++r) {
      const int i2 = rb + (lane >> 4) * 4 + r;
      const bool live = (i2 < Ta);
      const int trow = live ? arow[i2] : 0;
#pragma unroll
      for (int nt = 0; nt < 4; ++nt) {
        if (live && mk[nt]) {
          float z = acc[nt][r] + bv[nt];
          float ta = aprob[(size_t)trow * VA + (colbase + nt * 16 + lrow)];
          lsum += fmaxf(z, 0.f) - z * ta + log1pf(__expf(-fabsf(z)));
        }
      }
    }
  }
#pragma unroll
  for (int m = 1; m < 64; m <<= 1) lsum += __shfl_xor(lsum, m);
  __shared__ float wred[4];
  if (lane == 0) wred[wave] = lsum;
  __syncthreads();
  if (threadIdx.x == 0)
    partial[blockIdx.y * gridDim.x + blockIdx.x] = wred[0] + wred[1] + wred[2] + wred[3];
}

// ---------------- per-row combine ----------------
__global__ __launch_bounds__(256) void combine2_kernel(
    const float* __restrict__ psS, const float* __restrict__ ps2S,
    const float* __restrict__ psP, const float* __restrict__ ps2P,
    const float* __restrict__ psM, const float* __restrict__ ps2M,
    const float* __restrict__ tlog,
    float* __restrict__ nll, float* __restrict__ sm, int T) {
  const int lane = threadIdx.x & 63;
  const int wave = threadIdx.x >> 6;
  const int t = blockIdx.x * 4 + wave;
  if (t >= T) return;

  float z = 0.f, s = 0.f;
#pragma unroll
  for (int i = lane; i < NVB_S; i += 64) {
    z += psS[(size_t)t * NVB_S + i];
    s += ps2S[(size_t)t * NVB_S + i];
  }
#pragma unroll
  for (int m = 1; m < 64; m <<= 1) { z += __shfl_xor(z, m); s += __shfl_xor(s, m); }
  if (lane == 0) {
    float lz = logf(z);
    nll[t] = lz - tlog[t];
    sm[t]  = (float)VS * lz - s;

    float zP = psP[t], sP = ps2P[t];
    float lzP = logf(zP);
    nll[TPAD + t] = lzP - tlog[TPAD + t];
    sm[TPAD + t]  = (float)VP * lzP - sP;

    float zM = psM[2 * t] + psM[2 * t + 1];
    float sM = ps2M[2 * t] + ps2M[2 * t + 1];
    float lzM = logf(zM);
    nll[2 * TPAD + t] = lzM - tlog[2 * TPAD + t];
    sm[2 * TPAD + t]  = (float)VM * lzM - sM;
  }
}

// ---------------- finalize ----------------
__global__ __launch_bounds__(256) void finalize_kernel(
    const float* __restrict__ nll, const float* __restrict__ sm,
    const float* __restrict__ affp, int naff, float* __restrict__ out, int T, int Ta) {
  __shared__ float red[256];
  const int tid = threadIdx.x;
  float nll_m[3], sm_m[3];
  for (int h2 = 0; h2 < 3; ++h2) {
    float a = 0.f, b = 0.f;
    for (int t = tid; t < T; t += 256) { a += nll[h2 * TPAD + t]; b += sm[h2 * TPAD + t]; }
    red[tid] = a; __syncthreads();
    for (int s = 128; s > 0; s >>= 1) { if (tid < s) red[tid] += red[tid + s]; __syncthreads(); }
    float asum = red[0]; __syncthreads();
    red[tid] = b; __syncthreads();
    for (int s = 128; s > 0; s >>= 1) { if (tid < s) red[tid] += red[tid + s]; __syncthreads(); }
    float bsm = red[0]; __syncthreads();
    nll_m[h2] = asum / (float)T;
    sm_m[h2]  = bsm / (float)T;
  }
  float av = 0.f;
  for (int i = tid; i < naff; i += 256) av += affp[i];
  red[tid] = av; __syncthreads();
  for (int s = 128; s > 0; s >>= 1) { if (tid < s) red[tid] += red[tid + s]; __syncthreads(); }
  if (tid == 0) {
    const float Vv[3] = {(float)VS, (float)VP, (float)VM};
    for (int h2 = 0; h2 < 3; ++h2) {
      float eps_i = 0.1f / (Vv[h2] - 1.f);
      out[h2] = (1.0f - 0.1f - eps_i) * nll_m[h2] + eps_i * sm_m[h2];
      out[4 + h2] = nll_m[h2];
    }
    out[3] = red[0] / ((float)Ta * (float)VA);
  }
}

// ---------------- host launcher ----------------
extern "C" void kernel_launch(void* const* d_in, const int* in_sizes, int n_in,
                              void* d_out, int out_size, void* d_ws, size_t ws_size,
                              hipStream_t stream) {
  const float* tr      = (const float*)d_in[0];
  const float* aprob   = (const float*)d_in[1];
  const int* stems     = (const int*)d_in[2];
  const int* postags   = (const int*)d_in[3];
  const int* morphs    = (const int*)d_in[4];
  const int* hsel      = (const int*)d_in[5];
  const int* tsel      = (const int*)d_in[6];
  const int* asel      = (const int*)d_in[7];
  const float* s_emb = (const float*)d_in[8],  *s_W = (const float*)d_in[9];
  const float* s_b   = (const float*)d_in[10], *s_g = (const float*)d_in[11];
  const float* s_be  = (const float*)d_in[12], *s_bias = (const float*)d_in[13];
  const float* p_emb = (const float*)d_in[14], *p_W = (const float*)d_in[15];
  const float* p_b   = (const float*)d_in[16], *p_g = (const float*)d_in[17];
  const float* p_be  = (const float*)d_in[18], *p_bias = (const float*)d_in[19];
  const float* m_emb = (const float*)d_in[20], *m_W = (const float*)d_in[21];
  const float* m_b   = (const float*)d_in[22], *m_g = (const float*)d_in[23];
  const float* m_be  = (const float*)d_in[24], *m_bias = (const float*)d_in[25];
  const float* a_emb = (const float*)d_in[26], *a_W = (const float*)d_in[27];
  const float* a_b   = (const float*)d_in[28], *a_g = (const float*)d_in[29];
  const float* a_be  = (const float*)d_in[30], *a_bias = (const float*)d_in[31];

  const int T  = in_sizes[5];   // 3576
  const int Ta = in_sizes[7];   // ~2688

  size_t off = 0;
  auto alloc = [&](size_t nbytes) -> char* {
    char* p = (char*)d_ws + off;
    off = (off + nbytes + 255) & ~(size_t)255;
    return p;
  };
  unsigned short* x    = (unsigned short*)alloc((size_t)TPAD * D_MODEL * 2);
  unsigned short* wtS  = (unsigned short*)alloc((size_t)DS_STEM * D_MODEL * 2);
  unsigned short* wtP  = (unsigned short*)alloc((size_t)DS_POS * D_MODEL * 2);
  unsigned short* wtM  = (unsigned short*)alloc((size_t)DS_MORPH * D_MODEL * 2);
  unsigned short* wtA  = (unsigned short*)alloc((size_t)DS_AFF * D_MODEL * 2);
  unsigned short* embS = (unsigned short*)alloc((size_t)VS_PAD * DS_STEM * 2);
  unsigned short* embP = (unsigned short*)alloc((size_t)VP_PAD * DS_POS * 2);
  unsigned short* embM = (unsigned short*)alloc((size_t)VM_PAD * DS_MORPH * 2);
  unsigned short* embA = (unsigned short*)alloc((size_t)VA_PAD * DS_AFF * 2);
  unsigned short* hS   = (unsigned short*)alloc((size_t)TPAD * DS_STEM * 2);
  unsigned short* hP   = (unsigned short*)alloc((size_t)TPAD * DS_POS * 2);
  unsigned short* hM   = (unsigned short*)alloc((size_t)TPAD * DS_MORPH * 2);
  unsigned short* hA   = (unsigned short*)alloc((size_t)TPAD * DS_AFF * 2);
  float* psS   = (float*)alloc((size_t)TPAD * NVB_S * 4);
  float* ps2S  = (float*)alloc((size_t)TPAD * NVB_S * 4);
  float* psP   = (float*)alloc((size_t)TPAD * NVB_P * 4);
  float* ps2P  = (float*)alloc((size_t)TPAD * NVB_P * 4);
  float* psM   = (float*)alloc((size_t)TPAD * NVB_M * 4);
  float* ps2M  = (float*)alloc((size_t)TPAD * NVB_M * 4);
  float* tlog  = (float*)alloc((size_t)3 * TPAD * 4);
  int*   tgtS  = (int*)alloc((size_t)TPAD * 4);
  int*   tgtP  = (int*)alloc((size_t)TPAD * 4);
  int*   tgtM  = (int*)alloc((size_t)TPAD * 4);
  int*   arow  = (int*)alloc((size_t)TPAD * 4);
  float* nllb  = (float*)alloc((size_t)3 * TPAD * 4);
  float* smb   = (float*)alloc((size_t)3 * TPAD * 4);
  float* affp  = (float*)alloc(512);
  (void)ws_size; (void)n_in; (void)out_size;

  // 1. gather + cast predictor states, pre-gather targets & affix rows
  gather_x_kernel<<<(TPAD * D_MODEL) / 256, 256, 0, stream>>>(
      tr, hsel, tsel, asel, stems, postags, morphs, x, tgtS, tgtP, tgtM, arow, T, Ta);
  // 2. fused W transposes -> [DS, 768] bf16
  transpose_all_kernel<<<491520 / 256, 256, 0, stream>>>(s_W, p_W, m_W, a_W, wtS, wtP, wtM, wtA);
  // 3. fused emb -> bf16 casts
  conv_emb_all_kernel<<<12704, 256, 0, stream>>>(s_emb, p_emb, m_emb, a_emb, embS, embP, embM, embA);
  // 4. head transforms
  head_stem_kernel<<<TPAD / 32, 128, 0, stream>>>(x, wtS, s_b, s_g, s_be, hS);
  head_pma_kernel<<<dim3(TPAD / 32, 3), 128, 0, stream>>>(
      x, wtP, p_b, p_g, p_be, hP, wtM, m_b, m_g, m_be, hM, wtA, a_b, a_g, a_be, hA);
  // 5. streaming softmax stats (sum-exp + sum-logit per row, per 256-col block)
  stats2_kernel<8><<<dim3(8, VS_PAD / 256), 256, 0, stream>>>(hS, embS, s_bias, psS, ps2S, VS, NVB_S);
  stats2_kernel<4><<<dim3(8, 1), 256, 0, stream>>>(hP, embP, p_bias, psP, ps2P, VP, NVB_P);
  stats2_kernel<4><<<dim3(8, 2), 256, 0, stream>>>(hM, embM, m_bias, psM, ps2M, VM, NVB_M);
  // 6. target logits (3 heads)
  tgtlog_kernel<<<dim3((T + 3) / 4, 3), 256, 0, stream>>>(
      hS, embS, s_bias, tgtS, hP, embP, p_bias, tgtP, hM, embM, m_bias, tgtM, tlog, T);
  // 7. affix BCE
  const int gaff = (Ta + 63) / 64;
  aff_bce_kernel<<<dim3(gaff, 2), 256, 0, stream>>>(hA, embA, a_bias, asel, arow, aprob, affp, Ta);
  // 8. per-row combine + final reduction
  combine2_kernel<<<(T + 3) / 4, 256, 0, stream>>>(psS, ps2S, psP, ps2P, psM, ps2M, tlog, nllb, smb, T);
  finalize_kernel<<<1, 256, 0, stream>>>(nllb, smb, affp, gaff * 2, (float*)d_out, T, Ta);
}

// Round 4
// 395.148 us; speedup vs baseline: 1.4797x; 1.4797x over previous
//
#include <hip/hip_runtime.h>
#include <cstdint>
#include <cstddef>

// MorphoGPT predictor loss, fully fused on-device. v4.
// Stem stats GEMM restructured: operand-swapped MFMA (A=emb, B=h) streams the
// 50k vocab dim while 64 tokens/wave stay in registers; exp-sums accumulate in
// per-lane registers -> no cross-lane/LDS/barrier work in the hot loop.
// Padded vocab rows contribute exp(0)=1 each, subtracted as a constant later.

typedef __attribute__((ext_vector_type(8))) __bf16 bf16x8;
typedef __attribute__((ext_vector_type(4))) float f32x4;
typedef __attribute__((ext_vector_type(4))) unsigned short u16x4;
typedef __attribute__((ext_vector_type(2))) unsigned short u16x2;

namespace {
constexpr int S_LEN   = 448;
constexpr int N_SEQ   = 8;
constexpr int D_MODEL = 768;
constexpr int TPAD    = 3584;      // padded token rows (T = 3576)
constexpr int VS = 50000, VP = 200, VM = 400, VA = 360;
constexpr int DS_STEM = 256, DS_POS = 128, DS_MORPH = 128, DS_AFF = 128;
constexpr int VS_PAD = 50176;      // 196 * 256 ; 3136 16-row tiles
constexpr int VP_PAD = 256;
constexpr int VM_PAD = 512;
constexpr int VA_PAD = 512;
constexpr int VCHUNK = 32;         // stem vocab chunks (psum cols)
constexpr int VITERS = 3136 / VCHUNK;  // 98 16-row tiles per chunk
constexpr float PAD_E = (float)(VS_PAD - VS);  // exp(0) contributions from pad rows
constexpr int NVB_P = 1;
constexpr int NVB_M = 2;
}

__device__ __forceinline__ unsigned short f2bf(float f) {
  unsigned int u = __float_as_uint(f);
  unsigned int r = (u + 0x7FFFu + ((u >> 16) & 1u)) >> 16;  // RNE
  return (unsigned short)r;
}
__device__ __forceinline__ float bf2f(unsigned short u) {
  return __uint_as_float(((unsigned int)u) << 16);
}

// ---------------- prep kernels ----------------

__global__ __launch_bounds__(256) void gather_x_kernel(
    const float* __restrict__ tr, const int* __restrict__ hsel,
    const int* __restrict__ tsel, const int* __restrict__ asel,
    const int* __restrict__ stems, const int* __restrict__ postags,
    const int* __restrict__ morphs,
    unsigned short* __restrict__ x, int* __restrict__ tgtS, int* __restrict__ tgtP,
    int* __restrict__ tgtM, int* __restrict__ arow, int T, int Ta) {
  const size_t e = (size_t)blockIdx.x * 256 + threadIdx.x;  // e < TPAD*768 exact
  const int t = (int)(e / D_MODEL);
  const int d = (int)(e % D_MODEL);
  float v = 0.f;
  if (t < T) {
    int idx = hsel[t];
    int n = idx / S_LEN, s = idx % S_LEN;
    v = tr[((size_t)s * N_SEQ + n) * D_MODEL + d];
  }
  x[e] = f2bf(v);
  if (e < (size_t)T) {
    int tt = tsel[e];
    tgtS[e] = stems[tt]; tgtP[e] = postags[tt]; tgtM[e] = morphs[tt];
  }
  if (e < (size_t)Ta) arow[e] = tsel[asel[e]];
}

__global__ __launch_bounds__(256) void transpose_all_kernel(
    const float* __restrict__ sW, const float* __restrict__ pW,
    const float* __restrict__ mW, const float* __restrict__ aW,
    unsigned short* __restrict__ wtS, unsigned short* __restrict__ wtP,
    unsigned short* __restrict__ wtM, unsigned short* __restrict__ wtA) {
  const int e = blockIdx.x * 256 + threadIdx.x;  // < 491520 exact
  const float* W; unsigned short* Wt; int DS; int local;
  if (e < 196608)      { W = sW; Wt = wtS; DS = 256; local = e; }
  else if (e < 294912) { W = pW; Wt = wtP; DS = 128; local = e - 196608; }
  else if (e < 393216) { W = mW; Wt = wtM; DS = 128; local = e - 294912; }
  else                 { W = aW; Wt = wtA; DS = 128; local = e - 393216; }
  const int n = local / D_MODEL, k = local % D_MODEL;
  Wt[local] = f2bf(W[(size_t)k * DS + n]);
}

__global__ __launch_bounds__(256) void conv_emb_all_kernel(
    const float* __restrict__ sE, const float* __restrict__ pE,
    const float* __restrict__ mE, const float* __restrict__ aE,
    unsigned short* __restrict__ dS, unsigned short* __restrict__ dP,
    unsigned short* __restrict__ dM, unsigned short* __restrict__ dA) {
  const size_t q = ((size_t)blockIdx.x * 256 + threadIdx.x) * 4;
  const float* src; unsigned short* dst; size_t local, real;
  if (q < 12845056)            { src = sE; dst = dS; local = q;            real = 12800000; }
  else if (q < 12877824)       { src = pE; dst = dP; local = q - 12845056; real = 25600; }
  else if (q < 12943360)       { src = mE; dst = dM; local = q - 12877824; real = 51200; }
  else                         { src = aE; dst = dA; local = q - 12943360; real = 46080; }
  float4 v = make_float4(0.f, 0.f, 0.f, 0.f);
  if (local < real) v = *(const float4*)(src + local);
  u16x4 o = { f2bf(v.x), f2bf(v.y), f2bf(v.z), f2bf(v.w) };
  *(u16x4*)(dst + local) = o;
}

// stem bias padded with zeros (pad rows then contribute exp(0)=1, fixed later)
__global__ __launch_bounds__(256) void pad_bias_kernel(
    const float* __restrict__ b, float* __restrict__ bp) {
  const int i = blockIdx.x * 256 + threadIdx.x;  // < VS_PAD exact
  bp[i] = (i < VS) ? b[i] : 0.f;
}

// ---------------- head transform: h = LN(gelu(x @ W + b)) * g + beta ----------------
template <int NT>
__device__ __forceinline__ void head_body(
    const unsigned short* __restrict__ x, const unsigned short* __restrict__ Wt,
    const float* __restrict__ bvec, const float* __restrict__ gvec,
    const float* __restrict__ betav, unsigned short* __restrict__ hout) {
  constexpr int DS = NT * 16;
  const int lane = threadIdx.x & 63;
  const int wave = threadIdx.x >> 6;           // 0..1 (128-thread block)
  const int row0 = blockIdx.x * 32 + wave * 16;
  const int lrow = lane & 15;
  const int lk8  = (lane >> 4) * 8;

  f32x4 acc[NT];
#pragma unroll
  for (int nt = 0; nt < NT; ++nt) acc[nt] = f32x4{0.f, 0.f, 0.f, 0.f};

  const unsigned short* xrow = x + (size_t)(row0 + lrow) * D_MODEL + lk8;
#pragma unroll
  for (int ks = 0; ks < 24; ++ks) {  // K = 768 = 24 * 32
    bf16x8 a = *(const bf16x8*)(xrow + ks * 32);
#pragma unroll
    for (int nt = 0; nt < NT; ++nt) {
      bf16x8 b = *(const bf16x8*)(Wt + (size_t)(nt * 16 + lrow) * D_MODEL + ks * 32 + lk8);
      acc[nt] = __builtin_amdgcn_mfma_f32_16x16x32_bf16(a, b, acc[nt], 0, 0, 0);
    }
  }

  float bb[NT], gg[NT], be[NT];
#pragma unroll
  for (int nt = 0; nt < NT; ++nt) {
    int c = nt * 16 + lrow;
    bb[nt] = bvec[c]; gg[nt] = gvec[c]; be[nt] = betav[c];
  }
#pragma unroll
  for (int r = 0; r < 4; ++r) {
    const int row = row0 + (lane >> 4) * 4 + r;
    float vals[NT];
    float s = 0.f, s2 = 0.f;
#pragma unroll
    for (int nt = 0; nt < NT; ++nt) {
      float v = acc[nt][r] + bb[nt];
      v = 0.5f * v * (1.f + erff(v * 0.70710678118654752f));  // exact erf-gelu
      vals[nt] = v; s += v; s2 += v * v;
    }
    s  += __shfl_xor(s, 1);  s  += __shfl_xor(s, 2);  s  += __shfl_xor(s, 4);  s  += __shfl_xor(s, 8);
    s2 += __shfl_xor(s2, 1); s2 += __shfl_xor(s2, 2); s2 += __shfl_xor(s2, 4); s2 += __shfl_xor(s2, 8);
    const float mean = s * (1.f / DS);
    const float var  = s2 * (1.f / DS) - mean * mean;
    const float rstd = rsqrtf(var + 1e-12f);
#pragma unroll
    for (int nt = 0; nt < NT; ++nt) {
      float o = (vals[nt] - mean) * rstd * gg[nt] + be[nt];
      hout[(size_t)row * DS + nt * 16 + lrow] = f2bf(o);
    }
  }
}

// all four heads in one dispatch: blockIdx.y selects {P, M, A, stem}
__global__ __launch_bounds__(128, 2) void head_all_kernel(
    const unsigned short* __restrict__ x,
    const unsigned short* __restrict__ wtS, const float* __restrict__ sb,
    const float* __restrict__ sg, const float* __restrict__ sbe, unsigned short* __restrict__ hS,
    const unsigned short* __restrict__ wtP, const float* __restrict__ pb,
    const float* __restrict__ pg, const float* __restrict__ pbe, unsigned short* __restrict__ hP,
    const unsigned short* __restrict__ wtM, const float* __restrict__ mb,
    const float* __restrict__ mg, const float* __restrict__ mbe, unsigned short* __restrict__ hM,
    const unsigned short* __restrict__ wtA, const float* __restrict__ ab,
    const float* __restrict__ ag, const float* __restrict__ abe, unsigned short* __restrict__ hA) {
  if (blockIdx.y == 3)      head_body<16>(x, wtS, sb, sg, sbe, hS);
  else if (blockIdx.y == 0) head_body<8>(x, wtP, pb, pg, pbe, hP);
  else if (blockIdx.y == 1) head_body<8>(x, wtM, mb, mg, mbe, hM);
  else                      head_body<8>(x, wtA, ab, ag, abe, hA);
}

// ---------------- stem stats: operand-swapped, vocab-streaming ----------------
// Wave owns 64 tokens (B operand in regs); streams 98 x 16 vocab rows per
// chunk. Per-lane esum/ssum registers; one 2-hop shfl reduce at the end.
__global__ __launch_bounds__(512, 2) void stem_stats_kernel(
    const unsigned short* __restrict__ h, const unsigned short* __restrict__ emb,
    const float* __restrict__ bpad, float* __restrict__ psum,
    float* __restrict__ psum2) {
  const int lane = threadIdx.x & 63;
  const int wave = threadIdx.x >> 6;   // 0..7
  const int lrow = lane & 15;
  const int hi   = lane >> 4;
  const int lk8  = hi * 8;
  const int tok0 = blockIdx.x * 512 + wave * 64;
  const int vbase0 = blockIdx.y * (VITERS * 16);

  bf16x8 hB[4][8];
#pragma unroll
  for (int tt = 0; tt < 4; ++tt)
#pragma unroll
    for (int ks = 0; ks < 8; ++ks)
      hB[tt][ks] = *(const bf16x8*)(h + (size_t)(tok0 + tt * 16 + lrow) * 256 + ks * 32 + lk8);

  float esum[4] = {0.f, 0.f, 0.f, 0.f};
  float ssum[4] = {0.f, 0.f, 0.f, 0.f};

#pragma unroll 2
  for (int it = 0; it < VITERS; ++it) {
    const int vb = vbase0 + it * 16;
    bf16x8 aA[8];
#pragma unroll
    for (int ks = 0; ks < 8; ++ks)
      aA[ks] = *(const bf16x8*)(emb + (size_t)(vb + lrow) * 256 + ks * 32 + lk8);
    const float4 bv = *(const float4*)(bpad + vb + hi * 4);
#pragma unroll
    for (int tt = 0; tt < 4; ++tt) {
      f32x4 acc = f32x4{0.f, 0.f, 0.f, 0.f};
#pragma unroll
      for (int ks = 0; ks < 8; ++ks)
        acc = __builtin_amdgcn_mfma_f32_16x16x32_bf16(aA[ks], hB[tt][ks], acc, 0, 0, 0);
      const float v0 = acc[0] + bv.x, v1 = acc[1] + bv.y;
      const float v2 = acc[2] + bv.z, v3 = acc[3] + bv.w;
      esum[tt] += (__expf(v0) + __expf(v1)) + (__expf(v2) + __expf(v3));
      ssum[tt] += (v0 + v1) + (v2 + v3);
    }
  }

#pragma unroll
  for (int tt = 0; tt < 4; ++tt) {
    float e = esum[tt], s = ssum[tt];
    e += __shfl_xor(e, 16); e += __shfl_xor(e, 32);
    s += __shfl_xor(s, 16); s += __shfl_xor(s, 32);
    if (hi == 0) {
      const int tok = tok0 + tt * 16 + lrow;
      psum [(size_t)tok * VCHUNK + blockIdx.y] = e;
      psum2[(size_t)tok * VCHUNK + blockIdx.y] = s;
    }
  }
}

// ---------------- small-head stats (P/M): emb cols in regs, 32 rows/block ----------------
template <int KS, int ITERS_>  // DK = KS*32
__global__ __launch_bounds__(256, 2) void stats2_kernel(
    const unsigned short* __restrict__ h, const unsigned short* __restrict__ emb,
    const float* __restrict__ bias, float* __restrict__ psum,
    float* __restrict__ psum2, int V, int NVB) {
  constexpr int DK = KS * 32;
  const int lane = threadIdx.x & 63;
  const int wave = threadIdx.x >> 6;
  const int colbase = blockIdx.y * 256 + wave * 64;
  const int row0 = blockIdx.x * (ITERS_ * 32);
  const int lrow = lane & 15;
  const int hi   = lane >> 4;
  const int lk8  = hi * 8;

  __shared__ float lds_e[4][32];
  __shared__ float lds_s[4][32];

  bf16x8 bfr[KS][4];
  float bv[4];
  bool mk[4];
#pragma unroll
  for (int nt = 0; nt < 4; ++nt) {
    int col = colbase + nt * 16 + lrow;
#pragma unroll
    for (int ks = 0; ks < KS; ++ks)
      bfr[ks][nt] = *(const bf16x8*)(emb + (size_t)col * DK + ks * 32 + lk8);
    mk[nt] = (col < V);
    bv[nt] = mk[nt] ? bias[col] : 0.f;
  }

  for (int it = 0; it < ITERS_; ++it) {
    const int rb = row0 + it * 32;
    f32x4 acc[2][4];
#pragma unroll
    for (int rt = 0; rt < 2; ++rt)
#pragma unroll
      for (int nt = 0; nt < 4; ++nt) acc[rt][nt] = f32x4{0.f, 0.f, 0.f, 0.f};

    const unsigned short* hrow = h + (size_t)(rb + lrow) * DK + lk8;
#pragma unroll
    for (int ks = 0; ks < KS; ++ks) {
#pragma unroll
      for (int rt = 0; rt < 2; ++rt) {
        bf16x8 a = *(const bf16x8*)(hrow + (size_t)rt * 16 * DK + ks * 32);
#pragma unroll
        for (int nt = 0; nt < 4; ++nt)
          acc[rt][nt] = __builtin_amdgcn_mfma_f32_16x16x32_bf16(a, bfr[ks][nt], acc[rt][nt], 0, 0, 0);
      }
    }

#pragma unroll
    for (int rt = 0; rt < 2; ++rt)
#pragma unroll
      for (int r = 0; r < 4; ++r) {
        float e = 0.f, s = 0.f;
#pragma unroll
        for (int nt = 0; nt < 4; ++nt) {
          float v = acc[rt][nt][r] + bv[nt];
          float ev = __expf(v);
          e += mk[nt] ? ev : 0.f;
          s += mk[nt] ? v : 0.f;
        }
        e += __shfl_xor(e, 1); e += __shfl_xor(e, 2); e += __shfl_xor(e, 4); e += __shfl_xor(e, 8);
        s += __shfl_xor(s, 1); s += __shfl_xor(s, 2); s += __shfl_xor(s, 4); s += __shfl_xor(s, 8);
        if (lrow == 0) {
          lds_e[wave][rt * 16 + hi * 4 + r] = e;
          lds_s[wave][rt * 16 + hi * 4 + r] = s;
        }
      }
    __syncthreads();
    if (threadIdx.x < 32) {
      const int rr = threadIdx.x;
      float e = lds_e[0][rr] + lds_e[1][rr] + lds_e[2][rr] + lds_e[3][rr];
      float s = lds_s[0][rr] + lds_s[1][rr] + lds_s[2][rr] + lds_s[3][rr];
      const int row = rb + rr;
      psum[(size_t)row * NVB + blockIdx.y]  = e;
      psum2[(size_t)row * NVB + blockIdx.y] = s;
    }
    __syncthreads();
  }
}

// ---------------- target logits ----------------
__global__ __launch_bounds__(256) void tgtlog_kernel(
    const unsigned short* __restrict__ hS, const unsigned short* __restrict__ embS,
    const float* __restrict__ bS, const int* __restrict__ tgtS,
    const unsigned short* __restrict__ hP, const unsigned short* __restrict__ embP,
    const float* __restrict__ bP, const int* __restrict__ tgtP,
    const unsigned short* __restrict__ hM, const unsigned short* __restrict__ embM,
    const float* __restrict__ bM, const int* __restrict__ tgtM,
    float* __restrict__ tgtlog, int T) {
  const int lane = threadIdx.x & 63;
  const int wave = threadIdx.x >> 6;
  const int t = blockIdx.x * 4 + wave;
  const int hd = blockIdx.y;
  if (t >= T) return;
  float dot = 0.f; float bvv = 0.f;
  if (hd == 0) {
    const int tg = tgtS[t];
    u16x4 hv = *(const u16x4*)(hS + (size_t)t * 256 + lane * 4);
    u16x4 ev = *(const u16x4*)(embS + (size_t)tg * 256 + lane * 4);
    dot = bf2f(hv[0]) * bf2f(ev[0]) + bf2f(hv[1]) * bf2f(ev[1]) +
          bf2f(hv[2]) * bf2f(ev[2]) + bf2f(hv[3]) * bf2f(ev[3]);
    bvv = bS[tg];
  } else if (hd == 1) {
    const int tg = tgtP[t];
    u16x2 hv = *(const u16x2*)(hP + (size_t)t * 128 + lane * 2);
    u16x2 ev = *(const u16x2*)(embP + (size_t)tg * 128 + lane * 2);
    dot = bf2f(hv[0]) * bf2f(ev[0]) + bf2f(hv[1]) * bf2f(ev[1]);
    bvv = bP[tg];
  } else {
    const int tg = tgtM[t];
    u16x2 hv = *(const u16x2*)(hM + (size_t)t * 128 + lane * 2);
    u16x2 ev = *(const u16x2*)(embM + (size_t)tg * 128 + lane * 2);
    dot = bf2f(hv[0]) * bf2f(ev[0]) + bf2f(hv[1]) * bf2f(ev[1]);
    bvv = bM[tg];
  }
#pragma unroll
  for (int m = 1; m < 64; m <<= 1) dot += __shfl_xor(dot, m);
  if (lane == 0) tgtlog[hd * TPAD + t] = dot + bvv;
}

// ---------------- affix head: BCE-with-logits (16 rows/block) ----------------
__global__ __launch_bounds__(256, 2) void aff_bce_kernel(
    const unsigned short* __restrict__ h, const unsigned short* __restrict__ emb,
    const float* __restrict__ bias, const int* __restrict__ asel,
    const int* __restrict__ arow, const float* __restrict__ aprob,
    float* __restrict__ partial, int Ta) {
  const int lane = threadIdx.x & 63;
  const int wave = threadIdx.x >> 6;
  const int colbase = blockIdx.y * 256 + wave * 64;
  const int lrow = lane & 15;
  const int lk8  = (lane >> 4) * 8;

  bf16x8 bfr[4][4];
  float bv[4];
  bool mk[4];
#pragma unroll
  for (int nt = 0; nt < 4; ++nt) {
    int col = colbase + nt * 16 + lrow;
#pragma unroll
    for (int ks = 0; ks < 4; ++ks)
      bfr[ks][nt] = *(const bf16x8*)(emb + (size_t)col * DS_AFF + ks * 32 + lk8);
    mk[nt] = (col < VA);
    bv[nt] = mk[nt] ? bias[col] : 0.f;
  }

  float lsum = 0.f;
  {
    const int rb = blockIdx.x * 16;
    const int ia = rb + lrow;
    const int srow = (ia < Ta) ? asel[ia] : 0;
    f32x4 acc[4];
#pragma unroll
    for (int nt = 0; nt < 4; ++nt) acc[nt] = f32x4{0.f, 0.f, 0.f, 0.f};
    const unsigned short* hrow = h + (size_t)srow * DS_AFF + lk8;
#pragma unroll
    for (int ks = 0; ks < 4; ++ks) {
      bf16x8 a = *(const bf16x8*)(hrow + ks * 32);
#pragma unroll
      for (int nt = 0; nt < 4; ++nt)
        acc[nt] = __builtin_amdgcn_mfma_f32_16x16x32_bf16(a, bfr[ks][nt], acc[nt], 0, 0, 0);
    }
#pragma unroll
    for (int r = 0; r < 4; ++r) {
      const int i2 = rb + (lane >> 4) * 4 + r;
      const bool live = (i2 < Ta);
      const int trow = live ? arow[i2] : 0;
#pragma unroll
      for (int nt = 0; nt < 4; ++nt) {
        if (live && mk[nt]) {
          float z = acc[nt][r] + bv[nt];
          float ta = aprob[(size_t)trow * VA + (colbase + nt * 16 + lrow)];
          lsum += fmaxf(z, 0.f) - z * ta + log1pf(__expf(-fabsf(z)));
        }
      }
    }
  }
#pragma unroll
  for (int m = 1; m < 64; m <<= 1) lsum += __shfl_xor(lsum, m);
  __shared__ float wred[4];
  if (lane == 0) wred[wave] = lsum;
  __syncthreads();
  if (threadIdx.x == 0)
    partial[blockIdx.y * gridDim.x + blockIdx.x] = wred[0] + wred[1] + wred[2] + wred[3];
}

// ---------------- per-row combine ----------------
__global__ __launch_bounds__(256) void combine2_kernel(
    const float* __restrict__ psS, const float* __restrict__ ps2S,
    const float* __restrict__ psP, const float* __restrict__ ps2P,
    const float* __restrict__ psM, const float* __restrict__ ps2M,
    const float* __restrict__ tlog,
    float* __restrict__ nll, float* __restrict__ sm, int T) {
  const int lane = threadIdx.x & 63;
  const int wave = threadIdx.x >> 6;
  const int t = blockIdx.x * 4 + wave;
  if (t >= T) return;

  float z = 0.f, s = 0.f;
  if (lane < VCHUNK) {
    z = psS[(size_t)t * VCHUNK + lane];
    s = ps2S[(size_t)t * VCHUNK + lane];
  }
#pragma unroll
  for (int m = 1; m < 64; m <<= 1) { z += __shfl_xor(z, m); s += __shfl_xor(s, m); }
  if (lane == 0) {
    z -= PAD_E;  // pad vocab rows contributed exp(0)=1 each
    float lz = logf(z);
    nll[t] = lz - tlog[t];
    sm[t]  = (float)VS * lz - s;

    float zP = psP[t], sP = ps2P[t];
    float lzP = logf(zP);
    nll[TPAD + t] = lzP - tlog[TPAD + t];
    sm[TPAD + t]  = (float)VP * lzP - sP;

    float zM = psM[2 * t] + psM[2 * t + 1];
    float sM = ps2M[2 * t] + ps2M[2 * t + 1];
    float lzM = logf(zM);
    nll[2 * TPAD + t] = lzM - tlog[2 * TPAD + t];
    sm[2 * TPAD + t]  = (float)VM * lzM - sM;
  }
}

// ---------------- finalize ----------------
__global__ __launch_bounds__(256) void finalize_kernel(
    const float* __restrict__ nll, const float* __restrict__ sm,
    const float* __restrict__ affp, int naff, float* __restrict__ out, int T, int Ta) {
  __shared__ float red[256];
  const int tid = threadIdx.x;
  float nll_m[3], sm_m[3];
  for (int h2 = 0; h2 < 3; ++h2) {
    float a = 0.f, b = 0.f;
    for (int t = tid; t < T; t += 256) { a += nll[h2 * TPAD + t]; b += sm[h2 * TPAD + t]; }
    red[tid] = a; __syncthreads();
    for (int s = 128; s > 0; s >>= 1) { if (tid < s) red[tid] += red[tid + s]; __syncthreads(); }
    float asum = red[0]; __syncthreads();
    red[tid] = b; __syncthreads();
    for (int s = 128; s > 0; s >>= 1) { if (tid < s) red[tid] += red[tid + s]; __syncthreads(); }
    float bsm = red[0]; __syncthreads();
    nll_m[h2] = asum / (float)T;
    sm_m[h2]  = bsm / (float)T;
  }
  float av = 0.f;
  for (int i = tid; i < naff; i += 256) av += affp[i];
  red[tid] = av; __syncthreads();
  for (int s = 128; s > 0; s >>= 1) { if (tid < s) red[tid] += red[tid + s]; __syncthreads(); }
  if (tid == 0) {
    const float Vv[3] = {(float)VS, (float)VP, (float)VM};
    for (int h2 = 0; h2 < 3; ++h2) {
      float eps_i = 0.1f / (Vv[h2] - 1.f);
      out[h2] = (1.0f - 0.1f - eps_i) * nll_m[h2] + eps_i * sm_m[h2];
      out[4 + h2] = nll_m[h2];
    }
    out[3] = red[0] / ((float)Ta * (float)VA);
  }
}

// ---------------- host launcher ----------------
extern "C" void kernel_launch(void* const* d_in, const int* in_sizes, int n_in,
                              void* d_out, int out_size, void* d_ws, size_t ws_size,
                              hipStream_t stream) {
  const float* tr      = (const float*)d_in[0];
  const float* aprob   = (const float*)d_in[1];
  const int* stems     = (const int*)d_in[2];
  const int* postags   = (const int*)d_in[3];
  const int* morphs    = (const int*)d_in[4];
  const int* hsel      = (const int*)d_in[5];
  const int* tsel      = (const int*)d_in[6];
  const int* asel      = (const int*)d_in[7];
  const float* s_emb = (const float*)d_in[8],  *s_W = (const float*)d_in[9];
  const float* s_b   = (const float*)d_in[10], *s_g = (const float*)d_in[11];
  const float* s_be  = (const float*)d_in[12], *s_bias = (const float*)d_in[13];
  const float* p_emb = (const float*)d_in[14], *p_W = (const float*)d_in[15];
  const float* p_b   = (const float*)d_in[16], *p_g = (const float*)d_in[17];
  const float* p_be  = (const float*)d_in[18], *p_bias = (const float*)d_in[19];
  const float* m_emb = (const float*)d_in[20], *m_W = (const float*)d_in[21];
  const float* m_b   = (const float*)d_in[22], *m_g = (const float*)d_in[23];
  const float* m_be  = (const float*)d_in[24], *m_bias = (const float*)d_in[25];
  const float* a_emb = (const float*)d_in[26], *a_W = (const float*)d_in[27];
  const float* a_b   = (const float*)d_in[28], *a_g = (const float*)d_in[29];
  const float* a_be  = (const float*)d_in[30], *a_bias = (const float*)d_in[31];

  const int T  = in_sizes[5];   // 3576
  const int Ta = in_sizes[7];   // ~2688

  size_t off = 0;
  auto alloc = [&](size_t nbytes) -> char* {
    char* p = (char*)d_ws + off;
    off = (off + nbytes + 255) & ~(size_t)255;
    return p;
  };
  unsigned short* x    = (unsigned short*)alloc((size_t)TPAD * D_MODEL * 2);
  unsigned short* wtS  = (unsigned short*)alloc((size_t)DS_STEM * D_MODEL * 2);
  unsigned short* wtP  = (unsigned short*)alloc((size_t)DS_POS * D_MODEL * 2);
  unsigned short* wtM  = (unsigned short*)alloc((size_t)DS_MORPH * D_MODEL * 2);
  unsigned short* wtA  = (unsigned short*)alloc((size_t)DS_AFF * D_MODEL * 2);
  unsigned short* embS = (unsigned short*)alloc((size_t)VS_PAD * DS_STEM * 2);
  unsigned short* embP = (unsigned short*)alloc((size_t)VP_PAD * DS_POS * 2);
  unsigned short* embM = (unsigned short*)alloc((size_t)VM_PAD * DS_MORPH * 2);
  unsigned short* embA = (unsigned short*)alloc((size_t)VA_PAD * DS_AFF * 2);
  unsigned short* hS   = (unsigned short*)alloc((size_t)TPAD * DS_STEM * 2);
  unsigned short* hP   = (unsigned short*)alloc((size_t)TPAD * DS_POS * 2);
  unsigned short* hM   = (unsigned short*)alloc((size_t)TPAD * DS_MORPH * 2);
  unsigned short* hA   = (unsigned short*)alloc((size_t)TPAD * DS_AFF * 2);
  float* bpadS = (float*)alloc((size_t)VS_PAD * 4);
  float* psS   = (float*)alloc((size_t)TPAD * VCHUNK * 4);
  float* ps2S  = (float*)alloc((size_t)TPAD * VCHUNK * 4);
  float* psP   = (float*)alloc((size_t)TPAD * NVB_P * 4);
  float* ps2P  = (float*)alloc((size_t)TPAD * NVB_P * 4);
  float* psM   = (float*)alloc((size_t)TPAD * NVB_M * 4);
  float* ps2M  = (float*)alloc((size_t)TPAD * NVB_M * 4);
  float* tlog  = (float*)alloc((size_t)3 * TPAD * 4);
  int*   tgtS  = (int*)alloc((size_t)TPAD * 4);
  int*   tgtP  = (int*)alloc((size_t)TPAD * 4);
  int*   tgtM  = (int*)alloc((size_t)TPAD * 4);
  int*   arow  = (int*)alloc((size_t)TPAD * 4);
  float* nllb  = (float*)alloc((size_t)3 * TPAD * 4);
  float* smb   = (float*)alloc((size_t)3 * TPAD * 4);
  float* affp  = (float*)alloc(2048);
  (void)ws_size; (void)n_in; (void)out_size;

  // 1. gather + cast predictor states, pre-gather targets & affix rows
  gather_x_kernel<<<(TPAD * D_MODEL) / 256, 256, 0, stream>>>(
      tr, hsel, tsel, asel, stems, postags, morphs, x, tgtS, tgtP, tgtM, arow, T, Ta);
  // 2. fused W transposes -> [DS, 768] bf16
  transpose_all_kernel<<<491520 / 256, 256, 0, stream>>>(s_W, p_W, m_W, a_W, wtS, wtP, wtM, wtA);
  // 3. fused emb -> bf16 casts ; padded stem bias
  conv_emb_all_kernel<<<12704, 256, 0, stream>>>(s_emb, p_emb, m_emb, a_emb, embS, embP, embM, embA);
  pad_bias_kernel<<<VS_PAD / 256, 256, 0, stream>>>(s_bias, bpadS);
  // 4. all head transforms in one dispatch
  head_all_kernel<<<dim3(TPAD / 32, 4), 128, 0, stream>>>(
      x, wtS, s_b, s_g, s_be, hS, wtP, p_b, p_g, p_be, hP,
      wtM, m_b, m_g, m_be, hM, wtA, a_b, a_g, a_be, hA);
  // 5. stem stats: vocab-streaming operand-swapped GEMM
  stem_stats_kernel<<<dim3(TPAD / 512, VCHUNK), 512, 0, stream>>>(hS, embS, bpadS, psS, ps2S);
  // 5b. small-head stats
  stats2_kernel<4, 1><<<dim3(TPAD / 32, 1), 256, 0, stream>>>(hP, embP, p_bias, psP, ps2P, VP, NVB_P);
  stats2_kernel<4, 1><<<dim3(TPAD / 32, 2), 256, 0, stream>>>(hM, embM, m_bias, psM, ps2M, VM, NVB_M);
  // 6. target logits (3 heads)
  tgtlog_kernel<<<dim3((T + 3) / 4, 3), 256, 0, stream>>>(
      hS, embS, s_bias, tgtS, hP, embP, p_bias, tgtP, hM, embM, m_bias, tgtM, tlog, T);
  // 7. affix BCE
  const int gaff = (Ta + 15) / 16;
  aff_bce_kernel<<<dim3(gaff, 2), 256, 0, stream>>>(hA, embA, a_bias, asel, arow, aprob, affp, Ta);
  // 8. per-row combine + final reduction
  combine2_kernel<<<(T + 3) / 4, 256, 0, stream>>>(psS, ps2S, psP, ps2P, psM, ps2M, tlog, nllb, smb, T);
  finalize_kernel<<<1, 256, 0, stream>>>(nllb, smb, affp, gaff * 2, (float*)d_out, T, Ta);
}

// Round 5
// 360.795 us; speedup vs baseline: 1.6206x; 1.0952x over previous
//
#include <hip/hip_runtime.h>
#include <cstdint>
#include <cstddef>

// MorphoGPT predictor loss, fully fused on-device. v5.
// stem_stats: XCD-swizzled 1D grid (7 blocks sharing a vocab chunk -> same
// XCD L2), explicit 2-stage register pipeline for the emb stream, setprio
// around the MFMA cluster. pad_bias folded into conv_emb_all.

typedef __attribute__((ext_vector_type(8))) __bf16 bf16x8;
typedef __attribute__((ext_vector_type(4))) float f32x4;
typedef __attribute__((ext_vector_type(4))) unsigned short u16x4;
typedef __attribute__((ext_vector_type(2))) unsigned short u16x2;

namespace {
constexpr int S_LEN   = 448;
constexpr int N_SEQ   = 8;
constexpr int D_MODEL = 768;
constexpr int TPAD    = 3584;      // padded token rows (T = 3576)
constexpr int VS = 50000, VP = 200, VM = 400, VA = 360;
constexpr int DS_STEM = 256, DS_POS = 128, DS_MORPH = 128, DS_AFF = 128;
constexpr int VS_PAD = 50176;      // 196 * 256 ; 3136 16-row tiles
constexpr int VP_PAD = 256;
constexpr int VM_PAD = 512;
constexpr int VA_PAD = 512;
constexpr int VCHUNK = 32;         // stem vocab chunks (psum cols)
constexpr int VITERS = 3136 / VCHUNK;  // 98 16-row tiles per chunk
constexpr float PAD_E = (float)(VS_PAD - VS);  // exp(0) contributions from pad rows
constexpr int NVB_P = 1;
constexpr int NVB_M = 2;
}

__device__ __forceinline__ unsigned short f2bf(float f) {
  unsigned int u = __float_as_uint(f);
  unsigned int r = (u + 0x7FFFu + ((u >> 16) & 1u)) >> 16;  // RNE
  return (unsigned short)r;
}
__device__ __forceinline__ float bf2f(unsigned short u) {
  return __uint_as_float(((unsigned int)u) << 16);
}

// ---------------- prep kernels ----------------

__global__ __launch_bounds__(256) void gather_x_kernel(
    const float* __restrict__ tr, const int* __restrict__ hsel,
    const int* __restrict__ tsel, const int* __restrict__ asel,
    const int* __restrict__ stems, const int* __restrict__ postags,
    const int* __restrict__ morphs,
    unsigned short* __restrict__ x, int* __restrict__ tgtS, int* __restrict__ tgtP,
    int* __restrict__ tgtM, int* __restrict__ arow, int T, int Ta) {
  const size_t e = (size_t)blockIdx.x * 256 + threadIdx.x;  // e < TPAD*768 exact
  const int t = (int)(e / D_MODEL);
  const int d = (int)(e % D_MODEL);
  float v = 0.f;
  if (t < T) {
    int idx = hsel[t];
    int n = idx / S_LEN, s = idx % S_LEN;
    v = tr[((size_t)s * N_SEQ + n) * D_MODEL + d];
  }
  x[e] = f2bf(v);
  if (e < (size_t)T) {
    int tt = tsel[e];
    tgtS[e] = stems[tt]; tgtP[e] = postags[tt]; tgtM[e] = morphs[tt];
  }
  if (e < (size_t)Ta) arow[e] = tsel[asel[e]];
}

__global__ __launch_bounds__(256) void transpose_all_kernel(
    const float* __restrict__ sW, const float* __restrict__ pW,
    const float* __restrict__ mW, const float* __restrict__ aW,
    unsigned short* __restrict__ wtS, unsigned short* __restrict__ wtP,
    unsigned short* __restrict__ wtM, unsigned short* __restrict__ wtA) {
  const int e = blockIdx.x * 256 + threadIdx.x;  // < 491520 exact
  const float* W; unsigned short* Wt; int DS; int local;
  if (e < 196608)      { W = sW; Wt = wtS; DS = 256; local = e; }
  else if (e < 294912) { W = pW; Wt = wtP; DS = 128; local = e - 196608; }
  else if (e < 393216) { W = mW; Wt = wtM; DS = 128; local = e - 294912; }
  else                 { W = aW; Wt = wtA; DS = 128; local = e - 393216; }
  const int n = local / D_MODEL, k = local % D_MODEL;
  Wt[local] = f2bf(W[(size_t)k * DS + n]);
}

// emb casts + padded stem bias, all in one dispatch.
__global__ __launch_bounds__(256) void conv_emb_all_kernel(
    const float* __restrict__ sE, const float* __restrict__ pE,
    const float* __restrict__ mE, const float* __restrict__ aE,
    const float* __restrict__ sb,
    unsigned short* __restrict__ dS, unsigned short* __restrict__ dP,
    unsigned short* __restrict__ dM, unsigned short* __restrict__ dA,
    float* __restrict__ bp) {
  const size_t q = ((size_t)blockIdx.x * 256 + threadIdx.x) * 4;  // < 13059072 exact
  if (q >= 13008896) {  // padded stem bias region (f32 -> f32)
    const size_t local = q - 13008896;  // < VS_PAD
    float4 v = make_float4(0.f, 0.f, 0.f, 0.f);
    if (local < (size_t)VS) v = *(const float4*)(sb + local);  // VS % 4 == 0
    *(float4*)(bp + local) = v;
    return;
  }
  const float* src; unsigned short* dst; size_t local, real;
  if (q < 12845056)            { src = sE; dst = dS; local = q;            real = 12800000; }
  else if (q < 12877824)       { src = pE; dst = dP; local = q - 12845056; real = 25600; }
  else if (q < 12943360)       { src = mE; dst = dM; local = q - 12877824; real = 51200; }
  else                         { src = aE; dst = dA; local = q - 12943360; real = 46080; }
  float4 v = make_float4(0.f, 0.f, 0.f, 0.f);
  if (local < real) v = *(const float4*)(src + local);
  u16x4 o = { f2bf(v.x), f2bf(v.y), f2bf(v.z), f2bf(v.w) };
  *(u16x4*)(dst + local) = o;
}

// ---------------- head transform: h = LN(gelu(x @ W + b)) * g + beta ----------------
template <int NT>
__device__ __forceinline__ void head_body(
    const unsigned short* __restrict__ x, const unsigned short* __restrict__ Wt,
    const float* __restrict__ bvec, const float* __restrict__ gvec,
    const float* __restrict__ betav, unsigned short* __restrict__ hout) {
  constexpr int DS = NT * 16;
  const int lane = threadIdx.x & 63;
  const int wave = threadIdx.x >> 6;           // 0..1 (128-thread block)
  const int row0 = blockIdx.x * 32 + wave * 16;
  const int lrow = lane & 15;
  const int lk8  = (lane >> 4) * 8;

  f32x4 acc[NT];
#pragma unroll
  for (int nt = 0; nt < NT; ++nt) acc[nt] = f32x4{0.f, 0.f, 0.f, 0.f};

  const unsigned short* xrow = x + (size_t)(row0 + lrow) * D_MODEL + lk8;
#pragma unroll
  for (int ks = 0; ks < 24; ++ks) {  // K = 768 = 24 * 32
    bf16x8 a = *(const bf16x8*)(xrow + ks * 32);
#pragma unroll
    for (int nt = 0; nt < NT; ++nt) {
      bf16x8 b = *(const bf16x8*)(Wt + (size_t)(nt * 16 + lrow) * D_MODEL + ks * 32 + lk8);
      acc[nt] = __builtin_amdgcn_mfma_f32_16x16x32_bf16(a, b, acc[nt], 0, 0, 0);
    }
  }

  float bb[NT], gg[NT], be[NT];
#pragma unroll
  for (int nt = 0; nt < NT; ++nt) {
    int c = nt * 16 + lrow;
    bb[nt] = bvec[c]; gg[nt] = gvec[c]; be[nt] = betav[c];
  }
#pragma unroll
  for (int r = 0; r < 4; ++r) {
    const int row = row0 + (lane >> 4) * 4 + r;
    float vals[NT];
    float s = 0.f, s2 = 0.f;
#pragma unroll
    for (int nt = 0; nt < NT; ++nt) {
      float v = acc[nt][r] + bb[nt];
      v = 0.5f * v * (1.f + erff(v * 0.70710678118654752f));  // exact erf-gelu
      vals[nt] = v; s += v; s2 += v * v;
    }
    s  += __shfl_xor(s, 1);  s  += __shfl_xor(s, 2);  s  += __shfl_xor(s, 4);  s  += __shfl_xor(s, 8);
    s2 += __shfl_xor(s2, 1); s2 += __shfl_xor(s2, 2); s2 += __shfl_xor(s2, 4); s2 += __shfl_xor(s2, 8);
    const float mean = s * (1.f / DS);
    const float var  = s2 * (1.f / DS) - mean * mean;
    const float rstd = rsqrtf(var + 1e-12f);
#pragma unroll
    for (int nt = 0; nt < NT; ++nt) {
      float o = (vals[nt] - mean) * rstd * gg[nt] + be[nt];
      hout[(size_t)row * DS + nt * 16 + lrow] = f2bf(o);
    }
  }
}

// all four heads in one dispatch: blockIdx.y selects {P, M, A, stem}
__global__ __launch_bounds__(128, 2) void head_all_kernel(
    const unsigned short* __restrict__ x,
    const unsigned short* __restrict__ wtS, const float* __restrict__ sb,
    const float* __restrict__ sg, const float* __restrict__ sbe, unsigned short* __restrict__ hS,
    const unsigned short* __restrict__ wtP, const float* __restrict__ pb,
    const float* __restrict__ pg, const float* __restrict__ pbe, unsigned short* __restrict__ hP,
    const unsigned short* __restrict__ wtM, const float* __restrict__ mb,
    const float* __restrict__ mg, const float* __restrict__ mbe, unsigned short* __restrict__ hM,
    const unsigned short* __restrict__ wtA, const float* __restrict__ ab,
    const float* __restrict__ ag, const float* __restrict__ abe, unsigned short* __restrict__ hA) {
  if (blockIdx.y == 3)      head_body<16>(x, wtS, sb, sg, sbe, hS);
  else if (blockIdx.y == 0) head_body<8>(x, wtP, pb, pg, pbe, hP);
  else if (blockIdx.y == 1) head_body<8>(x, wtM, mb, mg, mbe, hM);
  else                      head_body<8>(x, wtA, ab, ag, abe, hA);
}

// ---------------- stem stats: operand-swapped, vocab-streaming, XCD-swizzled ----------------
// 1D grid of 224 blocks (1/CU). Decompose so the 7 blocks sharing a vocab
// chunk get the same bid%8 (same XCD): bx = (bid>>3)%7, by = (bid>>3)/7*8 + bid&7.
// Explicit 2-stage register pipeline on the emb stream.
__global__ __launch_bounds__(512, 2) void stem_stats_kernel(
    const unsigned short* __restrict__ h, const unsigned short* __restrict__ emb,
    const float* __restrict__ bpad, float* __restrict__ psum,
    float* __restrict__ psum2) {
  const int f   = blockIdx.x;          // 0..223
  const int k2  = f >> 3;              // 0..27
  const int bx  = k2 % 7;              // token group
  const int by  = (k2 / 7) * 8 + (f & 7);  // vocab chunk 0..31, 7 sharers same XCD
  const int lane = threadIdx.x & 63;
  const int wave = threadIdx.x >> 6;   // 0..7
  const int lrow = lane & 15;
  const int hi   = lane >> 4;
  const int lk8  = hi * 8;
  const int tok0 = bx * 512 + wave * 64;
  const int vbase0 = by * (VITERS * 16);

  bf16x8 hB[4][8];
#pragma unroll
  for (int tt = 0; tt < 4; ++tt)
#pragma unroll
    for (int ks = 0; ks < 8; ++ks)
      hB[tt][ks] = *(const bf16x8*)(h + (size_t)(tok0 + tt * 16 + lrow) * 256 + ks * 32 + lk8);

  float esum[4] = {0.f, 0.f, 0.f, 0.f};
  float ssum[4] = {0.f, 0.f, 0.f, 0.f};

  const unsigned short* ebase = emb + (size_t)lrow * 256 + lk8;

  bf16x8 a0[8], a1[8];
  float4 b0, b1;

  auto loadt = [&](bf16x8 (&A)[8], float4& B, int vb) {
#pragma unroll
    for (int ks = 0; ks < 8; ++ks)
      A[ks] = *(const bf16x8*)(ebase + (size_t)vb * 256 + ks * 32);
    B = *(const float4*)(bpad + vb + hi * 4);
  };
  auto compute = [&](const bf16x8 (&A)[8], const float4& B) {
    f32x4 acc[4];
    __builtin_amdgcn_s_setprio(1);
#pragma unroll
    for (int tt = 0; tt < 4; ++tt) {
      acc[tt] = f32x4{0.f, 0.f, 0.f, 0.f};
#pragma unroll
      for (int ks = 0; ks < 8; ++ks)
        acc[tt] = __builtin_amdgcn_mfma_f32_16x16x32_bf16(A[ks], hB[tt][ks], acc[tt], 0, 0, 0);
    }
    __builtin_amdgcn_s_setprio(0);
#pragma unroll
    for (int tt = 0; tt < 4; ++tt) {
      const float v0 = acc[tt][0] + B.x, v1 = acc[tt][1] + B.y;
      const float v2 = acc[tt][2] + B.z, v3 = acc[tt][3] + B.w;
      esum[tt] += (__expf(v0) + __expf(v1)) + (__expf(v2) + __expf(v3));
      ssum[tt] += (v0 + v1) + (v2 + v3);
    }
  };

  loadt(a0, b0, vbase0);                          // prologue
  for (int it = 0; it < VITERS; it += 2) {        // VITERS = 98 (even)
    loadt(a1, b1, vbase0 + (it + 1) * 16);        // prefetch tile it+1
    compute(a0, b0);                              // compute tile it
    const int vb2 = (it + 2 < VITERS) ? vbase0 + (it + 2) * 16 : vbase0;
    loadt(a0, b0, vb2);                           // prefetch tile it+2 (dummy on last)
    compute(a1, b1);                              // compute tile it+1
  }

#pragma unroll
  for (int tt = 0; tt < 4; ++tt) {
    float e = esum[tt], s = ssum[tt];
    e += __shfl_xor(e, 16); e += __shfl_xor(e, 32);
    s += __shfl_xor(s, 16); s += __shfl_xor(s, 32);
    if (hi == 0) {
      const int tok = tok0 + tt * 16 + lrow;
      psum [(size_t)tok * VCHUNK + by] = e;
      psum2[(size_t)tok * VCHUNK + by] = s;
    }
  }
}

// ---------------- small-head stats (P/M): emb cols in regs, 32 rows/block ----------------
template <int KS, int ITERS_>  // DK = KS*32
__global__ __launch_bounds__(256, 2) void stats2_kernel(
    const unsigned short* __restrict__ h, const unsigned short* __restrict__ emb,
    const float* __restrict__ bias, float* __restrict__ psum,
    float* __restrict__ psum2, int V, int NVB) {
  constexpr int DK = KS * 32;
  const int lane = threadIdx.x & 63;
  const int wave = threadIdx.x >> 6;
  const int colbase = blockIdx.y * 256 + wave * 64;
  const int row0 = blockIdx.x * (ITERS_ * 32);
  const int lrow = lane & 15;
  const int hi   = lane >> 4;
  const int lk8  = hi * 8;

  __shared__ float lds_e[4][32];
  __shared__ float lds_s[4][32];

  bf16x8 bfr[KS][4];
  float bv[4];
  bool mk[4];
#pragma unroll
  for (int nt = 0; nt < 4; ++nt) {
    int col = colbase + nt * 16 + lrow;
#pragma unroll
    for (int ks = 0; ks < KS; ++ks)
      bfr[ks][nt] = *(const bf16x8*)(emb + (size_t)col * DK + ks * 32 + lk8);
    mk[nt] = (col < V);
    bv[nt] = mk[nt] ? bias[col] : 0.f;
  }

  for (int it = 0; it < ITERS_; ++it) {
    const int rb = row0 + it * 32;
    f32x4 acc[2][4];
#pragma unroll
    for (int rt = 0; rt < 2; ++rt)
#pragma unroll
      for (int nt = 0; nt < 4; ++nt) acc[rt][nt] = f32x4{0.f, 0.f, 0.f, 0.f};

    const unsigned short* hrow = h + (size_t)(rb + lrow) * DK + lk8;
#pragma unroll
    for (int ks = 0; ks < KS; ++ks) {
#pragma unroll
      for (int rt = 0; rt < 2; ++rt) {
        bf16x8 a = *(const bf16x8*)(hrow + (size_t)rt * 16 * DK + ks * 32);
#pragma unroll
        for (int nt = 0; nt < 4; ++nt)
          acc[rt][nt] = __builtin_amdgcn_mfma_f32_16x16x32_bf16(a, bfr[ks][nt], acc[rt][nt], 0, 0, 0);
      }
    }

#pragma unroll
    for (int rt = 0; rt < 2; ++rt)
#pragma unroll
      for (int r = 0; r < 4; ++r) {
        float e = 0.f, s = 0.f;
#pragma unroll
        for (int nt = 0; nt < 4; ++nt) {
          float v = acc[rt][nt][r] + bv[nt];
          float ev = __expf(v);
          e += mk[nt] ? ev : 0.f;
          s += mk[nt] ? v : 0.f;
        }
        e += __shfl_xor(e, 1); e += __shfl_xor(e, 2); e += __shfl_xor(e, 4); e += __shfl_xor(e, 8);
        s += __shfl_xor(s, 1); s += __shfl_xor(s, 2); s += __shfl_xor(s, 4); s += __shfl_xor(s, 8);
        if (lrow == 0) {
          lds_e[wave][rt * 16 + hi * 4 + r] = e;
          lds_s[wave][rt * 16 + hi * 4 + r] = s;
        }
      }
    __syncthreads();
    if (threadIdx.x < 32) {
      const int rr = threadIdx.x;
      float e = lds_e[0][rr] + lds_e[1][rr] + lds_e[2][rr] + lds_e[3][rr];
      float s = lds_s[0][rr] + lds_s[1][rr] + lds_s[2][rr] + lds_s[3][rr];
      const int row = rb + rr;
      psum[(size_t)row * NVB + blockIdx.y]  = e;
      psum2[(size_t)row * NVB + blockIdx.y] = s;
    }
    __syncthreads();
  }
}

// ---------------- target logits ----------------
__global__ __launch_bounds__(256) void tgtlog_kernel(
    const unsigned short* __restrict__ hS, const unsigned short* __restrict__ embS,
    const float* __restrict__ bS, const int* __restrict__ tgtS,
    const unsigned short* __restrict__ hP, const unsigned short* __restrict__ embP,
    const float* __restrict__ bP, const int* __restrict__ tgtP,
    const unsigned short* __restrict__ hM, const unsigned short* __restrict__ embM,
    const float* __restrict__ bM, const int* __restrict__ tgtM,
    float* __restrict__ tgtlog, int T) {
  const int lane = threadIdx.x & 63;
  const int wave = threadIdx.x >> 6;
  const int t = blockIdx.x * 4 + wave;
  const int hd = blockIdx.y;
  if (t >= T) return;
  float dot = 0.f; float bvv = 0.f;
  if (hd == 0) {
    const int tg = tgtS[t];
    u16x4 hv = *(const u16x4*)(hS + (size_t)t * 256 + lane * 4);
    u16x4 ev = *(const u16x4*)(embS + (size_t)tg * 256 + lane * 4);
    dot = bf2f(hv[0]) * bf2f(ev[0]) + bf2f(hv[1]) * bf2f(ev[1]) +
          bf2f(hv[2]) * bf2f(ev[2]) + bf2f(hv[3]) * bf2f(ev[3]);
    bvv = bS[tg];
  } else if (hd == 1) {
    const int tg = tgtP[t];
    u16x2 hv = *(const u16x2*)(hP + (size_t)t * 128 + lane * 2);
    u16x2 ev = *(const u16x2*)(embP + (size_t)tg * 128 + lane * 2);
    dot = bf2f(hv[0]) * bf2f(ev[0]) + bf2f(hv[1]) * bf2f(ev[1]);
    bvv = bP[tg];
  } else {
    const int tg = tgtM[t];
    u16x2 hv = *(const u16x2*)(hM + (size_t)t * 128 + lane * 2);
    u16x2 ev = *(const u16x2*)(embM + (size_t)tg * 128 + lane * 2);
    dot = bf2f(hv[0]) * bf2f(ev[0]) + bf2f(hv[1]) * bf2f(ev[1]);
    bvv = bM[tg];
  }
#pragma unroll
  for (int m = 1; m < 64; m <<= 1) dot += __shfl_xor(dot, m);
  if (lane == 0) tgtlog[hd * TPAD + t] = dot + bvv;
}

// ---------------- affix head: BCE-with-logits (16 rows/block) ----------------
__global__ __launch_bounds__(256, 2) void aff_bce_kernel(
    const unsigned short* __restrict__ h, const unsigned short* __restrict__ emb,
    const float* __restrict__ bias, const int* __restrict__ asel,
    const int* __restrict__ arow, const float* __restrict__ aprob,
    float* __restrict__ partial, int Ta) {
  const int lane = threadIdx.x & 63;
  const int wave = threadIdx.x >> 6;
  const int colbase = blockIdx.y * 256 + wave * 64;
  const int lrow = lane & 15;
  const int lk8  = (lane >> 4) * 8;

  bf16x8 bfr[4][4];
  float bv[4];
  bool mk[4];
#pragma unroll
  for (int nt = 0; nt < 4; ++nt) {
    int col = colbase + nt * 16 + lrow;
#pragma unroll
    for (int ks = 0; ks < 4; ++ks)
      bfr[ks][nt] = *(const bf16x8*)(emb + (size_t)col * DS_AFF + ks * 32 + lk8);
    mk[nt] = (col < VA);
    bv[nt] = mk[nt] ? bias[col] : 0.f;
  }

  float lsum = 0.f;
  {
    const int rb = blockIdx.x * 16;
    const int ia = rb + lrow;
    const int srow = (ia < Ta) ? asel[ia] : 0;
    f32x4 acc[4];
#pragma unroll
    for (int nt = 0; nt < 4; ++nt) acc[nt] = f32x4{0.f, 0.f, 0.f, 0.f};
    const unsigned short* hrow = h + (size_t)srow * DS_AFF + lk8;
#pragma unroll
    for (int ks = 0; ks < 4; ++ks) {
      bf16x8 a = *(const bf16x8*)(hrow + ks * 32);
#pragma unroll
      for (int nt = 0; nt < 4; ++nt)
        acc[nt] = __builtin_amdgcn_mfma_f32_16x16x32_bf16(a, bfr[ks][nt], acc[nt], 0, 0, 0);
    }
#pragma unroll
    for (int r = 0; r < 4; ++r) {
      const int i2 = rb + (lane >> 4) * 4 + r;
      const bool live = (i2 < Ta);
      const int trow = live ? arow[i2] : 0;
#pragma unroll
      for (int nt = 0; nt < 4; ++nt) {
        if (live && mk[nt]) {
          float z = acc[nt][r] + bv[nt];
          float ta = aprob[(size_t)trow * VA + (colbase + nt * 16 + lrow)];
          lsum += fmaxf(z, 0.f) - z * ta + log1pf(__expf(-fabsf(z)));
        }
      }
    }
  }
#pragma unroll
  for (int m = 1; m < 64; m <<= 1) lsum += __shfl_xor(lsum, m);
  __shared__ float wred[4];
  if (lane == 0) wred[wave] = lsum;
  __syncthreads();
  if (threadIdx.x == 0)
    partial[blockIdx.y * gridDim.x + blockIdx.x] = wred[0] + wred[1] + wred[2] + wred[3];
}

// ---------------- per-row combine ----------------
__global__ __launch_bounds__(256) void combine2_kernel(
    const float* __restrict__ psS, const float* __restrict__ ps2S,
    const float* __restrict__ psP, const float* __restrict__ ps2P,
    const float* __restrict__ psM, const float* __restrict__ ps2M,
    const float* __restrict__ tlog,
    float* __restrict__ nll, float* __restrict__ sm, int T) {
  const int lane = threadIdx.x & 63;
  const int wave = threadIdx.x >> 6;
  const int t = blockIdx.x * 4 + wave;
  if (t >= T) return;

  float z = 0.f, s = 0.f;
  if (lane < VCHUNK) {
    z = psS[(size_t)t * VCHUNK + lane];
    s = ps2S[(size_t)t * VCHUNK + lane];
  }
#pragma unroll
  for (int m = 1; m < 64; m <<= 1) { z += __shfl_xor(z, m); s += __shfl_xor(s, m); }
  if (lane == 0) {
    z -= PAD_E;  // pad vocab rows contributed exp(0)=1 each
    float lz = logf(z);
    nll[t] = lz - tlog[t];
    sm[t]  = (float)VS * lz - s;

    float zP = psP[t], sP = ps2P[t];
    float lzP = logf(zP);
    nll[TPAD + t] = lzP - tlog[TPAD + t];
    sm[TPAD + t]  = (float)VP * lzP - sP;

    float zM = psM[2 * t] + psM[2 * t + 1];
    float sM = ps2M[2 * t] + ps2M[2 * t + 1];
    float lzM = logf(zM);
    nll[2 * TPAD + t] = lzM - tlog[2 * TPAD + t];
    sm[2 * TPAD + t]  = (float)VM * lzM - sM;
  }
}

// ---------------- finalize ----------------
__global__ __launch_bounds__(256) void finalize_kernel(
    const float* __restrict__ nll, const float* __restrict__ sm,
    const float* __restrict__ affp, int naff, float* __restrict__ out, int T, int Ta) {
  __shared__ float red[256];
  const int tid = threadIdx.x;
  float nll_m[3], sm_m[3];
  for (int h2 = 0; h2 < 3; ++h2) {
    float a = 0.f, b = 0.f;
    for (int t = tid; t < T; t += 256) { a += nll[h2 * TPAD + t]; b += sm[h2 * TPAD + t]; }
    red[tid] = a; __syncthreads();
    for (int s = 128; s > 0; s >>= 1) { if (tid < s) red[tid] += red[tid + s]; __syncthreads(); }
    float asum = red[0]; __syncthreads();
    red[tid] = b; __syncthreads();
    for (int s = 128; s > 0; s >>= 1) { if (tid < s) red[tid] += red[tid + s]; __syncthreads(); }
    float bsm = red[0]; __syncthreads();
    nll_m[h2] = asum / (float)T;
    sm_m[h2]  = bsm / (float)T;
  }
  float av = 0.f;
  for (int i = tid; i < naff; i += 256) av += affp[i];
  red[tid] = av; __syncthreads();
  for (int s = 128; s > 0; s >>= 1) { if (tid < s) red[tid] += red[tid + s]; __syncthreads(); }
  if (tid == 0) {
    const float Vv[3] = {(float)VS, (float)VP, (float)VM};
    for (int h2 = 0; h2 < 3; ++h2) {
      float eps_i = 0.1f / (Vv[h2] - 1.f);
      out[h2] = (1.0f - 0.1f - eps_i) * nll_m[h2] + eps_i * sm_m[h2];
      out[4 + h2] = nll_m[h2];
    }
    out[3] = red[0] / ((float)Ta * (float)VA);
  }
}

// ---------------- host launcher ----------------
extern "C" void kernel_launch(void* const* d_in, const int* in_sizes, int n_in,
                              void* d_out, int out_size, void* d_ws, size_t ws_size,
                              hipStream_t stream) {
  const float* tr      = (const float*)d_in[0];
  const float* aprob   = (const float*)d_in[1];
  const int* stems     = (const int*)d_in[2];
  const int* postags   = (const int*)d_in[3];
  const int* morphs    = (const int*)d_in[4];
  const int* hsel      = (const int*)d_in[5];
  const int* tsel      = (const int*)d_in[6];
  const int* asel      = (const int*)d_in[7];
  const float* s_emb = (const float*)d_in[8],  *s_W = (const float*)d_in[9];
  const float* s_b   = (const float*)d_in[10], *s_g = (const float*)d_in[11];
  const float* s_be  = (const float*)d_in[12], *s_bias = (const float*)d_in[13];
  const float* p_emb = (const float*)d_in[14], *p_W = (const float*)d_in[15];
  const float* p_b   = (const float*)d_in[16], *p_g = (const float*)d_in[17];
  const float* p_be  = (const float*)d_in[18], *p_bias = (const float*)d_in[19];
  const float* m_emb = (const float*)d_in[20], *m_W = (const float*)d_in[21];
  const float* m_b   = (const float*)d_in[22], *m_g = (const float*)d_in[23];
  const float* m_be  = (const float*)d_in[24], *m_bias = (const float*)d_in[25];
  const float* a_emb = (const float*)d_in[26], *a_W = (const float*)d_in[27];
  const float* a_b   = (const float*)d_in[28], *a_g = (const float*)d_in[29];
  const float* a_be  = (const float*)d_in[30], *a_bias = (const float*)d_in[31];

  const int T  = in_sizes[5];   // 3576
  const int Ta = in_sizes[7];   // ~2688

  size_t off = 0;
  auto alloc = [&](size_t nbytes) -> char* {
    char* p = (char*)d_ws + off;
    off = (off + nbytes + 255) & ~(size_t)255;
    return p;
  };
  unsigned short* x    = (unsigned short*)alloc((size_t)TPAD * D_MODEL * 2);
  unsigned short* wtS  = (unsigned short*)alloc((size_t)DS_STEM * D_MODEL * 2);
  unsigned short* wtP  = (unsigned short*)alloc((size_t)DS_POS * D_MODEL * 2);
  unsigned short* wtM  = (unsigned short*)alloc((size_t)DS_MORPH * D_MODEL * 2);
  unsigned short* wtA  = (unsigned short*)alloc((size_t)DS_AFF * D_MODEL * 2);
  unsigned short* embS = (unsigned short*)alloc((size_t)VS_PAD * DS_STEM * 2);
  unsigned short* embP = (unsigned short*)alloc((size_t)VP_PAD * DS_POS * 2);
  unsigned short* embM = (unsigned short*)alloc((size_t)VM_PAD * DS_MORPH * 2);
  unsigned short* embA = (unsigned short*)alloc((size_t)VA_PAD * DS_AFF * 2);
  unsigned short* hS   = (unsigned short*)alloc((size_t)TPAD * DS_STEM * 2);
  unsigned short* hP   = (unsigned short*)alloc((size_t)TPAD * DS_POS * 2);
  unsigned short* hM   = (unsigned short*)alloc((size_t)TPAD * DS_MORPH * 2);
  unsigned short* hA   = (unsigned short*)alloc((size_t)TPAD * DS_AFF * 2);
  float* bpadS = (float*)alloc((size_t)VS_PAD * 4);
  float* psS   = (float*)alloc((size_t)TPAD * VCHUNK * 4);
  float* ps2S  = (float*)alloc((size_t)TPAD * VCHUNK * 4);
  float* psP   = (float*)alloc((size_t)TPAD * NVB_P * 4);
  float* ps2P  = (float*)alloc((size_t)TPAD * NVB_P * 4);
  float* psM   = (float*)alloc((size_t)TPAD * NVB_M * 4);
  float* ps2M  = (float*)alloc((size_t)TPAD * NVB_M * 4);
  float* tlog  = (float*)alloc((size_t)3 * TPAD * 4);
  int*   tgtS  = (int*)alloc((size_t)TPAD * 4);
  int*   tgtP  = (int*)alloc((size_t)TPAD * 4);
  int*   tgtM  = (int*)alloc((size_t)TPAD * 4);
  int*   arow  = (int*)alloc((size_t)TPAD * 4);
  float* nllb  = (float*)alloc((size_t)3 * TPAD * 4);
  float* smb   = (float*)alloc((size_t)3 * TPAD * 4);
  float* affp  = (float*)alloc(2048);
  (void)ws_size; (void)n_in; (void)out_size;

  // 1. gather + cast predictor states, pre-gather targets & affix rows
  gather_x_kernel<<<(TPAD * D_MODEL) / 256, 256, 0, stream>>>(
      tr, hsel, tsel, asel, stems, postags, morphs, x, tgtS, tgtP, tgtM, arow, T, Ta);
  // 2. fused W transposes -> [DS, 768] bf16
  transpose_all_kernel<<<491520 / 256, 256, 0, stream>>>(s_W, p_W, m_W, a_W, wtS, wtP, wtM, wtA);
  // 3. fused emb -> bf16 casts + padded stem bias
  conv_emb_all_kernel<<<12753, 256, 0, stream>>>(
      s_emb, p_emb, m_emb, a_emb, s_bias, embS, embP, embM, embA, bpadS);
  // 4. all head transforms in one dispatch
  head_all_kernel<<<dim3(TPAD / 32, 4), 128, 0, stream>>>(
      x, wtS, s_b, s_g, s_be, hS, wtP, p_b, p_g, p_be, hP,
      wtM, m_b, m_g, m_be, hM, wtA, a_b, a_g, a_be, hA);
  // 5. stem stats: vocab-streaming operand-swapped GEMM, XCD-swizzled
  stem_stats_kernel<<<7 * VCHUNK, 512, 0, stream>>>(hS, embS, bpadS, psS, ps2S);
  // 5b. small-head stats
  stats2_kernel<4, 1><<<dim3(TPAD / 32, 1), 256, 0, stream>>>(hP, embP, p_bias, psP, ps2P, VP, NVB_P);
  stats2_kernel<4, 1><<<dim3(TPAD / 32, 2), 256, 0, stream>>>(hM, embM, m_bias, psM, ps2M, VM, NVB_M);
  // 6. target logits (3 heads)
  tgtlog_kernel<<<dim3((T + 3) / 4, 3), 256, 0, stream>>>(
      hS, embS, s_bias, tgtS, hP, embP, p_bias, tgtP, hM, embM, m_bias, tgtM, tlog, T);
  // 7. affix BCE
  const int gaff = (Ta + 15) / 16;
  aff_bce_kernel<<<dim3(gaff, 2), 256, 0, stream>>>(hA, embA, a_bias, asel, arow, aprob, affp, Ta);
  // 8. per-row combine + final reduction
  combine2_kernel<<<(T + 3) / 4, 256, 0, stream>>>(psS, ps2S, psP, ps2P, psM, ps2M, tlog, nllb, smb, T);
  finalize_kernel<<<1, 256, 0, stream>>>(nllb, smb, affp, gaff * 2, (float*)d_out, T, Ta);
}

// Round 6
// 273.891 us; speedup vs baseline: 2.1347x; 1.3173x over previous
//
#include <hip/hip_runtime.h>
#include <cstdint>
#include <cstddef>

// MorphoGPT predictor loss, fully fused on-device. v6.
// stem_stats: LDS-staged emb tile (global_load_lds w16, one 8KB tile per block
// per iter, 8x less global traffic than per-wave loads), double-buffered with
// T3 2-phase schedule, row-XOR swizzle (linear LDS dest + pre-swizzled global
// source + swizzled ds_read). Epilogue math identical to verified v5.

typedef __attribute__((ext_vector_type(8))) __bf16 bf16x8;
typedef __attribute__((ext_vector_type(4))) float f32x4;
typedef __attribute__((ext_vector_type(4))) unsigned short u16x4;
typedef __attribute__((ext_vector_type(2))) unsigned short u16x2;

namespace {
constexpr int S_LEN   = 448;
constexpr int N_SEQ   = 8;
constexpr int D_MODEL = 768;
constexpr int TPAD    = 3584;      // padded token rows (T = 3576)
constexpr int VS = 50000, VP = 200, VM = 400, VA = 360;
constexpr int DS_STEM = 256, DS_POS = 128, DS_MORPH = 128, DS_AFF = 128;
constexpr int VS_PAD = 50176;      // 196 * 256 ; 3136 16-row tiles
constexpr int VP_PAD = 256;
constexpr int VM_PAD = 512;
constexpr int VA_PAD = 512;
constexpr int VCHUNK = 32;         // stem vocab chunks (psum cols)
constexpr int VITERS = 3136 / VCHUNK;  // 98 16-row tiles per chunk
constexpr float PAD_E = (float)(VS_PAD - VS);  // exp(0) contributions from pad rows
constexpr int NVB_P = 1;
constexpr int NVB_M = 2;
}

__device__ __forceinline__ unsigned short f2bf(float f) {
  unsigned int u = __float_as_uint(f);
  unsigned int r = (u + 0x7FFFu + ((u >> 16) & 1u)) >> 16;  // RNE
  return (unsigned short)r;
}
__device__ __forceinline__ float bf2f(unsigned short u) {
  return __uint_as_float(((unsigned int)u) << 16);
}

// ---------------- prep kernels ----------------

__global__ __launch_bounds__(256) void gather_x_kernel(
    const float* __restrict__ tr, const int* __restrict__ hsel,
    const int* __restrict__ tsel, const int* __restrict__ asel,
    const int* __restrict__ stems, const int* __restrict__ postags,
    const int* __restrict__ morphs,
    unsigned short* __restrict__ x, int* __restrict__ tgtS, int* __restrict__ tgtP,
    int* __restrict__ tgtM, int* __restrict__ arow, int T, int Ta) {
  const size_t e = (size_t)blockIdx.x * 256 + threadIdx.x;  // e < TPAD*768 exact
  const int t = (int)(e / D_MODEL);
  const int d = (int)(e % D_MODEL);
  float v = 0.f;
  if (t < T) {
    int idx = hsel[t];
    int n = idx / S_LEN, s = idx % S_LEN;
    v = tr[((size_t)s * N_SEQ + n) * D_MODEL + d];
  }
  x[e] = f2bf(v);
  if (e < (size_t)T) {
    int tt = tsel[e];
    tgtS[e] = stems[tt]; tgtP[e] = postags[tt]; tgtM[e] = morphs[tt];
  }
  if (e < (size_t)Ta) arow[e] = tsel[asel[e]];
}

__global__ __launch_bounds__(256) void transpose_all_kernel(
    const float* __restrict__ sW, const float* __restrict__ pW,
    const float* __restrict__ mW, const float* __restrict__ aW,
    unsigned short* __restrict__ wtS, unsigned short* __restrict__ wtP,
    unsigned short* __restrict__ wtM, unsigned short* __restrict__ wtA) {
  const int e = blockIdx.x * 256 + threadIdx.x;  // < 491520 exact
  const float* W; unsigned short* Wt; int DS; int local;
  if (e < 196608)      { W = sW; Wt = wtS; DS = 256; local = e; }
  else if (e < 294912) { W = pW; Wt = wtP; DS = 128; local = e - 196608; }
  else if (e < 393216) { W = mW; Wt = wtM; DS = 128; local = e - 294912; }
  else                 { W = aW; Wt = wtA; DS = 128; local = e - 393216; }
  const int n = local / D_MODEL, k = local % D_MODEL;
  Wt[local] = f2bf(W[(size_t)k * DS + n]);
}

// emb casts + padded stem bias, all in one dispatch.
__global__ __launch_bounds__(256) void conv_emb_all_kernel(
    const float* __restrict__ sE, const float* __restrict__ pE,
    const float* __restrict__ mE, const float* __restrict__ aE,
    const float* __restrict__ sb,
    unsigned short* __restrict__ dS, unsigned short* __restrict__ dP,
    unsigned short* __restrict__ dM, unsigned short* __restrict__ dA,
    float* __restrict__ bp) {
  const size_t q = ((size_t)blockIdx.x * 256 + threadIdx.x) * 4;  // < 13059072 exact
  if (q >= 13008896) {  // padded stem bias region (f32 -> f32)
    const size_t local = q - 13008896;  // < VS_PAD
    float4 v = make_float4(0.f, 0.f, 0.f, 0.f);
    if (local < (size_t)VS) v = *(const float4*)(sb + local);  // VS % 4 == 0
    *(float4*)(bp + local) = v;
    return;
  }
  const float* src; unsigned short* dst; size_t local, real;
  if (q < 12845056)            { src = sE; dst = dS; local = q;            real = 12800000; }
  else if (q < 12877824)       { src = pE; dst = dP; local = q - 12845056; real = 25600; }
  else if (q < 12943360)       { src = mE; dst = dM; local = q - 12877824; real = 51200; }
  else                         { src = aE; dst = dA; local = q - 12943360; real = 46080; }
  float4 v = make_float4(0.f, 0.f, 0.f, 0.f);
  if (local < real) v = *(const float4*)(src + local);
  u16x4 o = { f2bf(v.x), f2bf(v.y), f2bf(v.z), f2bf(v.w) };
  *(u16x4*)(dst + local) = o;
}

// ---------------- head transform: h = LN(gelu(x @ W + b)) * g + beta ----------------
template <int NT>
__device__ __forceinline__ void head_body(
    const unsigned short* __restrict__ x, const unsigned short* __restrict__ Wt,
    const float* __restrict__ bvec, const float* __restrict__ gvec,
    const float* __restrict__ betav, unsigned short* __restrict__ hout) {
  constexpr int DS = NT * 16;
  const int lane = threadIdx.x & 63;
  const int wave = threadIdx.x >> 6;           // 0..1 (128-thread block)
  const int row0 = blockIdx.x * 32 + wave * 16;
  const int lrow = lane & 15;
  const int lk8  = (lane >> 4) * 8;

  f32x4 acc[NT];
#pragma unroll
  for (int nt = 0; nt < NT; ++nt) acc[nt] = f32x4{0.f, 0.f, 0.f, 0.f};

  const unsigned short* xrow = x + (size_t)(row0 + lrow) * D_MODEL + lk8;
#pragma unroll
  for (int ks = 0; ks < 24; ++ks) {  // K = 768 = 24 * 32
    bf16x8 a = *(const bf16x8*)(xrow + ks * 32);
#pragma unroll
    for (int nt = 0; nt < NT; ++nt) {
      bf16x8 b = *(const bf16x8*)(Wt + (size_t)(nt * 16 + lrow) * D_MODEL + ks * 32 + lk8);
      acc[nt] = __builtin_amdgcn_mfma_f32_16x16x32_bf16(a, b, acc[nt], 0, 0, 0);
    }
  }

  float bb[NT], gg[NT], be[NT];
#pragma unroll
  for (int nt = 0; nt < NT; ++nt) {
    int c = nt * 16 + lrow;
    bb[nt] = bvec[c]; gg[nt] = gvec[c]; be[nt] = betav[c];
  }
#pragma unroll
  for (int r = 0; r < 4; ++r) {
    const int row = row0 + (lane >> 4) * 4 + r;
    float vals[NT];
    float s = 0.f, s2 = 0.f;
#pragma unroll
    for (int nt = 0; nt < NT; ++nt) {
      float v = acc[nt][r] + bb[nt];
      v = 0.5f * v * (1.f + erff(v * 0.70710678118654752f));  // exact erf-gelu
      vals[nt] = v; s += v; s2 += v * v;
    }
    s  += __shfl_xor(s, 1);  s  += __shfl_xor(s, 2);  s  += __shfl_xor(s, 4);  s  += __shfl_xor(s, 8);
    s2 += __shfl_xor(s2, 1); s2 += __shfl_xor(s2, 2); s2 += __shfl_xor(s2, 4); s2 += __shfl_xor(s2, 8);
    const float mean = s * (1.f / DS);
    const float var  = s2 * (1.f / DS) - mean * mean;
    const float rstd = rsqrtf(var + 1e-12f);
#pragma unroll
    for (int nt = 0; nt < NT; ++nt) {
      float o = (vals[nt] - mean) * rstd * gg[nt] + be[nt];
      hout[(size_t)row * DS + nt * 16 + lrow] = f2bf(o);
    }
  }
}

// all four heads in one dispatch: blockIdx.y selects {P, M, A, stem}
__global__ __launch_bounds__(128, 2) void head_all_kernel(
    const unsigned short* __restrict__ x,
    const unsigned short* __restrict__ wtS, const float* __restrict__ sb,
    const float* __restrict__ sg, const float* __restrict__ sbe, unsigned short* __restrict__ hS,
    const unsigned short* __restrict__ wtP, const float* __restrict__ pb,
    const float* __restrict__ pg, const float* __restrict__ pbe, unsigned short* __restrict__ hP,
    const unsigned short* __restrict__ wtM, const float* __restrict__ mb,
    const float* __restrict__ mg, const float* __restrict__ mbe, unsigned short* __restrict__ hM,
    const unsigned short* __restrict__ wtA, const float* __restrict__ ab,
    const float* __restrict__ ag, const float* __restrict__ abe, unsigned short* __restrict__ hA) {
  if (blockIdx.y == 3)      head_body<16>(x, wtS, sb, sg, sbe, hS);
  else if (blockIdx.y == 0) head_body<8>(x, wtP, pb, pg, pbe, hP);
  else if (blockIdx.y == 1) head_body<8>(x, wtM, mb, mg, mbe, hM);
  else                      head_body<8>(x, wtA, ab, ag, abe, hA);
}

// ---------------- stem stats: operand-swapped, vocab-streaming, LDS-staged ----------------
// 1D grid of 224 blocks (1/CU), XCD-swizzled: the 7 blocks sharing a vocab
// chunk get the same bid%8 (same XCD L2). Per iter one 16x256 bf16 emb tile
// (8 KB) is staged once per block via global_load_lds w16 into a
// double-buffered LDS tile (linear dest + pre-swizzled source, row-XOR
// (row&7)<<4); waves ds_read_b128 with the same swizzle. 2-phase schedule:
// stage(next) -> compute(cur) -> __syncthreads (vmcnt drain + barrier).
__global__ __launch_bounds__(512, 2) void stem_stats_kernel(
    const unsigned short* __restrict__ h, const unsigned short* __restrict__ emb,
    const float* __restrict__ bpad, float* __restrict__ psum,
    float* __restrict__ psum2) {
  __shared__ alignas(16) unsigned short lbuf[2][16 * 256];  // 2 x 8 KB

  const int f   = blockIdx.x;          // 0..223
  const int k2  = f >> 3;              // 0..27
  const int bx  = k2 % 7;              // token group
  const int by  = (k2 / 7) * 8 + (f & 7);  // vocab chunk 0..31, 7 sharers same XCD
  const int tid  = threadIdx.x;
  const int lane = tid & 63;
  const int wave = tid >> 6;           // 0..7
  const int lrow = lane & 15;
  const int hi   = lane >> 4;
  const int lk8  = hi * 8;
  const int tok0 = bx * 512 + wave * 64;
  const int vbase0 = by * (VITERS * 16);

  // 64 tokens per wave, K=256, kept in registers for the whole kernel
  bf16x8 hB[4][8];
#pragma unroll
  for (int tt = 0; tt < 4; ++tt)
#pragma unroll
    for (int ks = 0; ks < 8; ++ks)
      hB[tt][ks] = *(const bf16x8*)(h + (size_t)(tok0 + tt * 16 + lrow) * 256 + ks * 32 + lk8);

  // staging source (pre-swizzled so linear LDS + swizzled read = correct data)
  const int dst16 = tid * 16;                         // dst byte within tile
  const int srow  = dst16 >> 9;                       // tile row (512 B/row)
  const int sbyte = dst16 ^ ((srow & 7) << 4);        // swizzled source byte
  const char* gs  = (const char*)emb + (size_t)vbase0 * 512 + sbyte;

  auto stage = [&](int buf, int it) {
    __builtin_amdgcn_global_load_lds(
        (const __attribute__((address_space(1))) unsigned int*)(gs + (size_t)it * 8192),
        (__attribute__((address_space(3))) unsigned int*)(&lbuf[buf][wave * 512]),
        16, 0, 0);
  };

  // swizzled ds_read offsets (tile-invariant)
  int loff[8];
#pragma unroll
  for (int ks = 0; ks < 8; ++ks)
    loff[ks] = (lrow * 512 + ks * 64 + hi * 16) ^ ((lrow & 7) << 4);

  float esum[4] = {0.f, 0.f, 0.f, 0.f};
  float ssum[4] = {0.f, 0.f, 0.f, 0.f};

  stage(0, 0);
  __syncthreads();   // tile 0 staged (vmcnt drained by syncthreads)

  int cur = 0;
  for (int it = 0; it < VITERS; ++it) {
    if (it + 1 < VITERS) stage(cur ^ 1, it + 1);   // prefetch next tile

    const int vb = vbase0 + it * 16;
    const float4 bv = *(const float4*)(bpad + vb + hi * 4);

    const char* lp = (const char*)&lbuf[cur][0];
    bf16x8 aA[8];
#pragma unroll
    for (int ks = 0; ks < 8; ++ks)
      aA[ks] = *(const bf16x8*)(lp + loff[ks]);

#pragma unroll
    for (int tt = 0; tt < 4; ++tt) {
      f32x4 acc = f32x4{0.f, 0.f, 0.f, 0.f};
#pragma unroll
      for (int ks = 0; ks < 8; ++ks)
        acc = __builtin_amdgcn_mfma_f32_16x16x32_bf16(aA[ks], hB[tt][ks], acc, 0, 0, 0);
      const float v0 = acc[0] + bv.x, v1 = acc[1] + bv.y;
      const float v2 = acc[2] + bv.z, v3 = acc[3] + bv.w;
      esum[tt] += (__expf(v0) + __expf(v1)) + (__expf(v2) + __expf(v3));
      ssum[tt] += (v0 + v1) + (v2 + v3);
    }

    __syncthreads();  // prefetch landed (vmcnt(0)) + all waves done reading cur
    cur ^= 1;
  }

#pragma unroll
  for (int tt = 0; tt < 4; ++tt) {
    float e = esum[tt], s = ssum[tt];
    e += __shfl_xor(e, 16); e += __shfl_xor(e, 32);
    s += __shfl_xor(s, 16); s += __shfl_xor(s, 32);
    if (hi == 0) {
      const int tok = tok0 + tt * 16 + lrow;
      psum [(size_t)tok * VCHUNK + by] = e;
      psum2[(size_t)tok * VCHUNK + by] = s;
    }
  }
}

// ---------------- small-head stats (P/M): emb cols in regs, 32 rows/block ----------------
template <int KS, int ITERS_>  // DK = KS*32
__global__ __launch_bounds__(256, 2) void stats2_kernel(
    const unsigned short* __restrict__ h, const unsigned short* __restrict__ emb,
    const float* __restrict__ bias, float* __restrict__ psum,
    float* __restrict__ psum2, int V, int NVB) {
  constexpr int DK = KS * 32;
  const int lane = threadIdx.x & 63;
  const int wave = threadIdx.x >> 6;
  const int colbase = blockIdx.y * 256 + wave * 64;
  const int row0 = blockIdx.x * (ITERS_ * 32);
  const int lrow = lane & 15;
  const int hi   = lane >> 4;
  const int lk8  = hi * 8;

  __shared__ float lds_e[4][32];
  __shared__ float lds_s[4][32];

  bf16x8 bfr[KS][4];
  float bv[4];
  bool mk[4];
#pragma unroll
  for (int nt = 0; nt < 4; ++nt) {
    int col = colbase + nt * 16 + lrow;
#pragma unroll
    for (int ks = 0; ks < KS; ++ks)
      bfr[ks][nt] = *(const bf16x8*)(emb + (size_t)col * DK + ks * 32 + lk8);
    mk[nt] = (col < V);
    bv[nt] = mk[nt] ? bias[col] : 0.f;
  }

  for (int it = 0; it < ITERS_; ++it) {
    const int rb = row0 + it * 32;
    f32x4 acc[2][4];
#pragma unroll
    for (int rt = 0; rt < 2; ++rt)
#pragma unroll
      for (int nt = 0; nt < 4; ++nt) acc[rt][nt] = f32x4{0.f, 0.f, 0.f, 0.f};

    const unsigned short* hrow = h + (size_t)(rb + lrow) * DK + lk8;
#pragma unroll
    for (int ks = 0; ks < KS; ++ks) {
#pragma unroll
      for (int rt = 0; rt < 2; ++rt) {
        bf16x8 a = *(const bf16x8*)(hrow + (size_t)rt * 16 * DK + ks * 32);
#pragma unroll
        for (int nt = 0; nt < 4; ++nt)
          acc[rt][nt] = __builtin_amdgcn_mfma_f32_16x16x32_bf16(a, bfr[ks][nt], acc[rt][nt], 0, 0, 0);
      }
    }

#pragma unroll
    for (int rt = 0; rt < 2; ++rt)
#pragma unroll
      for (int r = 0; r < 4; ++r) {
        float e = 0.f, s = 0.f;
#pragma unroll
        for (int nt = 0; nt < 4; ++nt) {
          float v = acc[rt][nt][r] + bv[nt];
          float ev = __expf(v);
          e += mk[nt] ? ev : 0.f;
          s += mk[nt] ? v : 0.f;
        }
        e += __shfl_xor(e, 1); e += __shfl_xor(e, 2); e += __shfl_xor(e, 4); e += __shfl_xor(e, 8);
        s += __shfl_xor(s, 1); s += __shfl_xor(s, 2); s += __shfl_xor(s, 4); s += __shfl_xor(s, 8);
        if (lrow == 0) {
          lds_e[wave][rt * 16 + hi * 4 + r] = e;
          lds_s[wave][rt * 16 + hi * 4 + r] = s;
        }
      }
    __syncthreads();
    if (threadIdx.x < 32) {
      const int rr = threadIdx.x;
      float e = lds_e[0][rr] + lds_e[1][rr] + lds_e[2][rr] + lds_e[3][rr];
      float s = lds_s[0][rr] + lds_s[1][rr] + lds_s[2][rr] + lds_s[3][rr];
      const int row = rb + rr;
      psum[(size_t)row * NVB + blockIdx.y]  = e;
      psum2[(size_t)row * NVB + blockIdx.y] = s;
    }
    __syncthreads();
  }
}

// ---------------- target logits ----------------
__global__ __launch_bounds__(256) void tgtlog_kernel(
    const unsigned short* __restrict__ hS, const unsigned short* __restrict__ embS,
    const float* __restrict__ bS, const int* __restrict__ tgtS,
    const unsigned short* __restrict__ hP, const unsigned short* __restrict__ embP,
    const float* __restrict__ bP, const int* __restrict__ tgtP,
    const unsigned short* __restrict__ hM, const unsigned short* __restrict__ embM,
    const float* __restrict__ bM, const int* __restrict__ tgtM,
    float* __restrict__ tgtlog, int T) {
  const int lane = threadIdx.x & 63;
  const int wave = threadIdx.x >> 6;
  const int t = blockIdx.x * 4 + wave;
  const int hd = blockIdx.y;
  if (t >= T) return;
  float dot = 0.f; float bvv = 0.f;
  if (hd == 0) {
    const int tg = tgtS[t];
    u16x4 hv = *(const u16x4*)(hS + (size_t)t * 256 + lane * 4);
    u16x4 ev = *(const u16x4*)(embS + (size_t)tg * 256 + lane * 4);
    dot = bf2f(hv[0]) * bf2f(ev[0]) + bf2f(hv[1]) * bf2f(ev[1]) +
          bf2f(hv[2]) * bf2f(ev[2]) + bf2f(hv[3]) * bf2f(ev[3]);
    bvv = bS[tg];
  } else if (hd == 1) {
    const int tg = tgtP[t];
    u16x2 hv = *(const u16x2*)(hP + (size_t)t * 128 + lane * 2);
    u16x2 ev = *(const u16x2*)(embP + (size_t)tg * 128 + lane * 2);
    dot = bf2f(hv[0]) * bf2f(ev[0]) + bf2f(hv[1]) * bf2f(ev[1]);
    bvv = bP[tg];
  } else {
    const int tg = tgtM[t];
    u16x2 hv = *(const u16x2*)(hM + (size_t)t * 128 + lane * 2);
    u16x2 ev = *(const u16x2*)(embM + (size_t)tg * 128 + lane * 2);
    dot = bf2f(hv[0]) * bf2f(ev[0]) + bf2f(hv[1]) * bf2f(ev[1]);
    bvv = bM[tg];
  }
#pragma unroll
  for (int m = 1; m < 64; m <<= 1) dot += __shfl_xor(dot, m);
  if (lane == 0) tgtlog[hd * TPAD + t] = dot + bvv;
}

// ---------------- affix head: BCE-with-logits (16 rows/block) ----------------
__global__ __launch_bounds__(256, 2) void aff_bce_kernel(
    const unsigned short* __restrict__ h, const unsigned short* __restrict__ emb,
    const float* __restrict__ bias, const int* __restrict__ asel,
    const int* __restrict__ arow, const float* __restrict__ aprob,
    float* __restrict__ partial, int Ta) {
  const int lane = threadIdx.x & 63;
  const int wave = threadIdx.x >> 6;
  const int colbase = blockIdx.y * 256 + wave * 64;
  const int lrow = lane & 15;
  const int lk8  = (lane >> 4) * 8;

  bf16x8 bfr[4][4];
  float bv[4];
  bool mk[4];
#pragma unroll
  for (int nt = 0; nt < 4; ++nt) {
    int col = colbase + nt * 16 + lrow;
#pragma unroll
    for (int ks = 0; ks < 4; ++ks)
      bfr[ks][nt] = *(const bf16x8*)(emb + (size_t)col * DS_AFF + ks * 32 + lk8);
    mk[nt] = (col < VA);
    bv[nt] = mk[nt] ? bias[col] : 0.f;
  }

  float lsum = 0.f;
  {
    const int rb = blockIdx.x * 16;
    const int ia = rb + lrow;
    const int srow = (ia < Ta) ? asel[ia] : 0;
    f32x4 acc[4];
#pragma unroll
    for (int nt = 0; nt < 4; ++nt) acc[nt] = f32x4{0.f, 0.f, 0.f, 0.f};
    const unsigned short* hrow = h + (size_t)srow * DS_AFF + lk8;
#pragma unroll
    for (int ks = 0; ks < 4; ++ks) {
      bf16x8 a = *(const bf16x8*)(hrow + ks * 32);
#pragma unroll
      for (int nt = 0; nt < 4; ++nt)
        acc[nt] = __builtin_amdgcn_mfma_f32_16x16x32_bf16(a, bfr[ks][nt], acc[nt], 0, 0, 0);
    }
#pragma unroll
    for (int r = 0; r < 4; ++r) {
      const int i2 = rb + (lane >> 4) * 4 + r;
      const bool live = (i2 < Ta);
      const int trow = live ? arow[i2] : 0;
#pragma unroll
      for (int nt = 0; nt < 4; ++nt) {
        if (live && mk[nt]) {
          float z = acc[nt][r] + bv[nt];
          float ta = aprob[(size_t)trow * VA + (colbase + nt * 16 + lrow)];
          lsum += fmaxf(z, 0.f) - z * ta + log1pf(__expf(-fabsf(z)));
        }
      }
    }
  }
#pragma unroll
  for (int m = 1; m < 64; m <<= 1) lsum += __shfl_xor(lsum, m);
  __shared__ float wred[4];
  if (lane == 0) wred[wave] = lsum;
  __syncthreads();
  if (threadIdx.x == 0)
    partial[blockIdx.y * gridDim.x + blockIdx.x] = wred[0] + wred[1] + wred[2] + wred[3];
}

// ---------------- per-row combine ----------------
__global__ __launch_bounds__(256) void combine2_kernel(
    const float* __restrict__ psS, const float* __restrict__ ps2S,
    const float* __restrict__ psP, const float* __restrict__ ps2P,
    const float* __restrict__ psM, const float* __restrict__ ps2M,
    const float* __restrict__ tlog,
    float* __restrict__ nll, float* __restrict__ sm, int T) {
  const int lane = threadIdx.x & 63;
  const int wave = threadIdx.x >> 6;
  const int t = blockIdx.x * 4 + wave;
  if (t >= T) return;

  float z = 0.f, s = 0.f;
  if (lane < VCHUNK) {
    z = psS[(size_t)t * VCHUNK + lane];
    s = ps2S[(size_t)t * VCHUNK + lane];
  }
#pragma unroll
  for (int m = 1; m < 64; m <<= 1) { z += __shfl_xor(z, m); s += __shfl_xor(s, m); }
  if (lane == 0) {
    z -= PAD_E;  // pad vocab rows contributed exp(0)=1 each
    float lz = logf(z);
    nll[t] = lz - tlog[t];
    sm[t]  = (float)VS * lz - s;

    float zP = psP[t], sP = ps2P[t];
    float lzP = logf(zP);
    nll[TPAD + t] = lzP - tlog[TPAD + t];
    sm[TPAD + t]  = (float)VP * lzP - sP;

    float zM = psM[2 * t] + psM[2 * t + 1];
    float sM = ps2M[2 * t] + ps2M[2 * t + 1];
    float lzM = logf(zM);
    nll[2 * TPAD + t] = lzM - tlog[2 * TPAD + t];
    sm[2 * TPAD + t]  = (float)VM * lzM - sM;
  }
}

// ---------------- finalize ----------------
__global__ __launch_bounds__(256) void finalize_kernel(
    const float* __restrict__ nll, const float* __restrict__ sm,
    const float* __restrict__ affp, int naff, float* __restrict__ out, int T, int Ta) {
  __shared__ float red[256];
  const int tid = threadIdx.x;
  float nll_m[3], sm_m[3];
  for (int h2 = 0; h2 < 3; ++h2) {
    float a = 0.f, b = 0.f;
    for (int t = tid; t < T; t += 256) { a += nll[h2 * TPAD + t]; b += sm[h2 * TPAD + t]; }
    red[tid] = a; __syncthreads();
    for (int s = 128; s > 0; s >>= 1) { if (tid < s) red[tid] += red[tid + s]; __syncthreads(); }
    float asum = red[0]; __syncthreads();
    red[tid] = b; __syncthreads();
    for (int s = 128; s > 0; s >>= 1) { if (tid < s) red[tid] += red[tid + s]; __syncthreads(); }
    float bsm = red[0]; __syncthreads();
    nll_m[h2] = asum / (float)T;
    sm_m[h2]  = bsm / (float)T;
  }
  float av = 0.f;
  for (int i = tid; i < naff; i += 256) av += affp[i];
  red[tid] = av; __syncthreads();
  for (int s = 128; s > 0; s >>= 1) { if (tid < s) red[tid] += red[tid + s]; __syncthreads(); }
  if (tid == 0) {
    const float Vv[3] = {(float)VS, (float)VP, (float)VM};
    for (int h2 = 0; h2 < 3; ++h2) {
      float eps_i = 0.1f / (Vv[h2] - 1.f);
      out[h2] = (1.0f - 0.1f - eps_i) * nll_m[h2] + eps_i * sm_m[h2];
      out[4 + h2] = nll_m[h2];
    }
    out[3] = red[0] / ((float)Ta * (float)VA);
  }
}

// ---------------- host launcher ----------------
extern "C" void kernel_launch(void* const* d_in, const int* in_sizes, int n_in,
                              void* d_out, int out_size, void* d_ws, size_t ws_size,
                              hipStream_t stream) {
  const float* tr      = (const float*)d_in[0];
  const float* aprob   = (const float*)d_in[1];
  const int* stems     = (const int*)d_in[2];
  const int* postags   = (const int*)d_in[3];
  const int* morphs    = (const int*)d_in[4];
  const int* hsel      = (const int*)d_in[5];
  const int* tsel      = (const int*)d_in[6];
  const int* asel      = (const int*)d_in[7];
  const float* s_emb = (const float*)d_in[8],  *s_W = (const float*)d_in[9];
  const float* s_b   = (const float*)d_in[10], *s_g = (const float*)d_in[11];
  const float* s_be  = (const float*)d_in[12], *s_bias = (const float*)d_in[13];
  const float* p_emb = (const float*)d_in[14], *p_W = (const float*)d_in[15];
  const float* p_b   = (const float*)d_in[16], *p_g = (const float*)d_in[17];
  const float* p_be  = (const float*)d_in[18], *p_bias = (const float*)d_in[19];
  const float* m_emb = (const float*)d_in[20], *m_W = (const float*)d_in[21];
  const float* m_b   = (const float*)d_in[22], *m_g = (const float*)d_in[23];
  const float* m_be  = (const float*)d_in[24], *m_bias = (const float*)d_in[25];
  const float* a_emb = (const float*)d_in[26], *a_W = (const float*)d_in[27];
  const float* a_b   = (const float*)d_in[28], *a_g = (const float*)d_in[29];
  const float* a_be  = (const float*)d_in[30], *a_bias = (const float*)d_in[31];

  const int T  = in_sizes[5];   // 3576
  const int Ta = in_sizes[7];   // ~2688

  size_t off = 0;
  auto alloc = [&](size_t nbytes) -> char* {
    char* p = (char*)d_ws + off;
    off = (off + nbytes + 255) & ~(size_t)255;
    return p;
  };
  unsigned short* x    = (unsigned short*)alloc((size_t)TPAD * D_MODEL * 2);
  unsigned short* wtS  = (unsigned short*)alloc((size_t)DS_STEM * D_MODEL * 2);
  unsigned short* wtP  = (unsigned short*)alloc((size_t)DS_POS * D_MODEL * 2);
  unsigned short* wtM  = (unsigned short*)alloc((size_t)DS_MORPH * D_MODEL * 2);
  unsigned short* wtA  = (unsigned short*)alloc((size_t)DS_AFF * D_MODEL * 2);
  unsigned short* embS = (unsigned short*)alloc((size_t)VS_PAD * DS_STEM * 2);
  unsigned short* embP = (unsigned short*)alloc((size_t)VP_PAD * DS_POS * 2);
  unsigned short* embM = (unsigned short*)alloc((size_t)VM_PAD * DS_MORPH * 2);
  unsigned short* embA = (unsigned short*)alloc((size_t)VA_PAD * DS_AFF * 2);
  unsigned short* hS   = (unsigned short*)alloc((size_t)TPAD * DS_STEM * 2);
  unsigned short* hP   = (unsigned short*)alloc((size_t)TPAD * DS_POS * 2);
  unsigned short* hM   = (unsigned short*)alloc((size_t)TPAD * DS_MORPH * 2);
  unsigned short* hA   = (unsigned short*)alloc((size_t)TPAD * DS_AFF * 2);
  float* bpadS = (float*)alloc((size_t)VS_PAD * 4);
  float* psS   = (float*)alloc((size_t)TPAD * VCHUNK * 4);
  float* ps2S  = (float*)alloc((size_t)TPAD * VCHUNK * 4);
  float* psP   = (float*)alloc((size_t)TPAD * NVB_P * 4);
  float* ps2P  = (float*)alloc((size_t)TPAD * NVB_P * 4);
  float* psM   = (float*)alloc((size_t)TPAD * NVB_M * 4);
  float* ps2M  = (float*)alloc((size_t)TPAD * NVB_M * 4);
  float* tlog  = (float*)alloc((size_t)3 * TPAD * 4);
  int*   tgtS  = (int*)alloc((size_t)TPAD * 4);
  int*   tgtP  = (int*)alloc((size_t)TPAD * 4);
  int*   tgtM  = (int*)alloc((size_t)TPAD * 4);
  int*   arow  = (int*)alloc((size_t)TPAD * 4);
  float* nllb  = (float*)alloc((size_t)3 * TPAD * 4);
  float* smb   = (float*)alloc((size_t)3 * TPAD * 4);
  float* affp  = (float*)alloc(2048);
  (void)ws_size; (void)n_in; (void)out_size;

  // 1. gather + cast predictor states, pre-gather targets & affix rows
  gather_x_kernel<<<(TPAD * D_MODEL) / 256, 256, 0, stream>>>(
      tr, hsel, tsel, asel, stems, postags, morphs, x, tgtS, tgtP, tgtM, arow, T, Ta);
  // 2. fused W transposes -> [DS, 768] bf16
  transpose_all_kernel<<<491520 / 256, 256, 0, stream>>>(s_W, p_W, m_W, a_W, wtS, wtP, wtM, wtA);
  // 3. fused emb -> bf16 casts + padded stem bias
  conv_emb_all_kernel<<<12753, 256, 0, stream>>>(
      s_emb, p_emb, m_emb, a_emb, s_bias, embS, embP, embM, embA, bpadS);
  // 4. all head transforms in one dispatch
  head_all_kernel<<<dim3(TPAD / 32, 4), 128, 0, stream>>>(
      x, wtS, s_b, s_g, s_be, hS, wtP, p_b, p_g, p_be, hP,
      wtM, m_b, m_g, m_be, hM, wtA, a_b, a_g, a_be, hA);
  // 5. stem stats: vocab-streaming operand-swapped GEMM, LDS-staged, XCD-swizzled
  stem_stats_kernel<<<7 * VCHUNK, 512, 0, stream>>>(hS, embS, bpadS, psS, ps2S);
  // 5b. small-head stats
  stats2_kernel<4, 1><<<dim3(TPAD / 32, 1), 256, 0, stream>>>(hP, embP, p_bias, psP, ps2P, VP, NVB_P);
  stats2_kernel<4, 1><<<dim3(TPAD / 32, 2), 256, 0, stream>>>(hM, embM, m_bias, psM, ps2M, VM, NVB_M);
  // 6. target logits (3 heads)
  tgtlog_kernel<<<dim3((T + 3) / 4, 3), 256, 0, stream>>>(
      hS, embS, s_bias, tgtS, hP, embP, p_bias, tgtP, hM, embM, m_bias, tgtM, tlog, T);
  // 7. affix BCE
  const int gaff = (Ta + 15) / 16;
  aff_bce_kernel<<<dim3(gaff, 2), 256, 0, stream>>>(hA, embA, a_bias, asel, arow, aprob, affp, Ta);
  // 8. per-row combine + final reduction
  combine2_kernel<<<(T + 3) / 4, 256, 0, stream>>>(psS, ps2S, psP, ps2P, psM, ps2M, tlog, nllb, smb, T);
  finalize_kernel<<<1, 256, 0, stream>>>(nllb, smb, affp, gaff * 2, (float*)d_out, T, Ta);
}

// Round 7
// 253.087 us; speedup vs baseline: 2.3102x; 1.0822x over previous
//
#include <hip/hip_runtime.h>
#include <cstdint>
#include <cstddef>

// MorphoGPT predictor loss, fully fused on-device. v7.
// stem_stats: 4-deep LDS pipeline with counted vmcnt(2) + raw s_barrier (T4) —
// stages stay in flight across barriers; bias staged to LDS so the K-loop has
// exactly one vmem op per iteration. All post-head small kernels (P/M stats,
// tgtlog, aff BCE) folded into the same dispatch as extra blocks that fill the
// 32 CUs stem leaves idle.

typedef __attribute__((ext_vector_type(8))) __bf16 bf16x8;
typedef __attribute__((ext_vector_type(4))) float f32x4;
typedef __attribute__((ext_vector_type(4))) unsigned short u16x4;
typedef __attribute__((ext_vector_type(2))) unsigned short u16x2;

namespace {
constexpr int S_LEN   = 448;
constexpr int N_SEQ   = 8;
constexpr int D_MODEL = 768;
constexpr int TPAD    = 3584;      // padded token rows (T = 3576)
constexpr int VS = 50000, VP = 200, VM = 400, VA = 360;
constexpr int DS_STEM = 256, DS_POS = 128, DS_MORPH = 128, DS_AFF = 128;
constexpr int VS_PAD = 50176;      // 196 * 256 ; 3136 16-row tiles
constexpr int VCHUNK = 32;         // stem vocab chunks (psum cols)
constexpr int VITERS = 3136 / VCHUNK;  // 98 16-row tiles per chunk
constexpr float PAD_E = (float)(VS_PAD - VS);  // exp(0) contributions from pad rows
constexpr int NVB_P = 1;
constexpr int NVB_M = 2;
}

__device__ __forceinline__ unsigned short f2bf(float f) {
  unsigned int u = __float_as_uint(f);
  unsigned int r = (u + 0x7FFFu + ((u >> 16) & 1u)) >> 16;  // RNE
  return (unsigned short)r;
}
__device__ __forceinline__ float bf2f(unsigned short u) {
  return __uint_as_float(((unsigned int)u) << 16);
}

// ---------------- prep kernels ----------------

__global__ __launch_bounds__(256) void gather_x_kernel(
    const float* __restrict__ tr, const int* __restrict__ hsel,
    const int* __restrict__ tsel, const int* __restrict__ asel,
    const int* __restrict__ stems, const int* __restrict__ postags,
    const int* __restrict__ morphs,
    unsigned short* __restrict__ x, int* __restrict__ tgtS, int* __restrict__ tgtP,
    int* __restrict__ tgtM, int* __restrict__ arow, int T, int Ta) {
  const size_t e = (size_t)blockIdx.x * 256 + threadIdx.x;  // e < TPAD*768 exact
  const int t = (int)(e / D_MODEL);
  const int d = (int)(e % D_MODEL);
  float v = 0.f;
  if (t < T) {
    int idx = hsel[t];
    int n = idx / S_LEN, s = idx % S_LEN;
    v = tr[((size_t)s * N_SEQ + n) * D_MODEL + d];
  }
  x[e] = f2bf(v);
  if (e < (size_t)T) {
    int tt = tsel[e];
    tgtS[e] = stems[tt]; tgtP[e] = postags[tt]; tgtM[e] = morphs[tt];
  }
  if (e < (size_t)Ta) arow[e] = tsel[asel[e]];
}

__global__ __launch_bounds__(256) void transpose_all_kernel(
    const float* __restrict__ sW, const float* __restrict__ pW,
    const float* __restrict__ mW, const float* __restrict__ aW,
    unsigned short* __restrict__ wtS, unsigned short* __restrict__ wtP,
    unsigned short* __restrict__ wtM, unsigned short* __restrict__ wtA) {
  const int e = blockIdx.x * 256 + threadIdx.x;  // < 491520 exact
  const float* W; unsigned short* Wt; int DS; int local;
  if (e < 196608)      { W = sW; Wt = wtS; DS = 256; local = e; }
  else if (e < 294912) { W = pW; Wt = wtP; DS = 128; local = e - 196608; }
  else if (e < 393216) { W = mW; Wt = wtM; DS = 128; local = e - 294912; }
  else                 { W = aW; Wt = wtA; DS = 128; local = e - 393216; }
  const int n = local / D_MODEL, k = local % D_MODEL;
  Wt[local] = f2bf(W[(size_t)k * DS + n]);
}

// emb casts + padded stem bias, all in one dispatch.
__global__ __launch_bounds__(256) void conv_emb_all_kernel(
    const float* __restrict__ sE, const float* __restrict__ pE,
    const float* __restrict__ mE, const float* __restrict__ aE,
    const float* __restrict__ sb,
    unsigned short* __restrict__ dS, unsigned short* __restrict__ dP,
    unsigned short* __restrict__ dM, unsigned short* __restrict__ dA,
    float* __restrict__ bp) {
  const size_t q = ((size_t)blockIdx.x * 256 + threadIdx.x) * 4;  // < 13059072 exact
  if (q >= 13008896) {  // padded stem bias region (f32 -> f32)
    const size_t local = q - 13008896;  // < VS_PAD
    float4 v = make_float4(0.f, 0.f, 0.f, 0.f);
    if (local < (size_t)VS) v = *(const float4*)(sb + local);  // VS % 4 == 0
    *(float4*)(bp + local) = v;
    return;
  }
  const float* src; unsigned short* dst; size_t local, real;
  if (q < 12845056)            { src = sE; dst = dS; local = q;            real = 12800000; }
  else if (q < 12877824)       { src = pE; dst = dP; local = q - 12845056; real = 25600; }
  else if (q < 12943360)       { src = mE; dst = dM; local = q - 12877824; real = 51200; }
  else                         { src = aE; dst = dA; local = q - 12943360; real = 46080; }
  float4 v = make_float4(0.f, 0.f, 0.f, 0.f);
  if (local < real) v = *(const float4*)(src + local);
  u16x4 o = { f2bf(v.x), f2bf(v.y), f2bf(v.z), f2bf(v.w) };
  *(u16x4*)(dst + local) = o;
}

// ---------------- head transform: h = LN(gelu(x @ W + b)) * g + beta ----------------
template <int NT>
__device__ __forceinline__ void head_body(
    const unsigned short* __restrict__ x, const unsigned short* __restrict__ Wt,
    const float* __restrict__ bvec, const float* __restrict__ gvec,
    const float* __restrict__ betav, unsigned short* __restrict__ hout) {
  constexpr int DS = NT * 16;
  const int lane = threadIdx.x & 63;
  const int wave = threadIdx.x >> 6;           // 0..1 (128-thread block)
  const int row0 = blockIdx.x * 32 + wave * 16;
  const int lrow = lane & 15;
  const int lk8  = (lane >> 4) * 8;

  f32x4 acc[NT];
#pragma unroll
  for (int nt = 0; nt < NT; ++nt) acc[nt] = f32x4{0.f, 0.f, 0.f, 0.f};

  const unsigned short* xrow = x + (size_t)(row0 + lrow) * D_MODEL + lk8;
#pragma unroll
  for (int ks = 0; ks < 24; ++ks) {  // K = 768 = 24 * 32
    bf16x8 a = *(const bf16x8*)(xrow + ks * 32);
#pragma unroll
    for (int nt = 0; nt < NT; ++nt) {
      bf16x8 b = *(const bf16x8*)(Wt + (size_t)(nt * 16 + lrow) * D_MODEL + ks * 32 + lk8);
      acc[nt] = __builtin_amdgcn_mfma_f32_16x16x32_bf16(a, b, acc[nt], 0, 0, 0);
    }
  }

  float bb[NT], gg[NT], be[NT];
#pragma unroll
  for (int nt = 0; nt < NT; ++nt) {
    int c = nt * 16 + lrow;
    bb[nt] = bvec[c]; gg[nt] = gvec[c]; be[nt] = betav[c];
  }
#pragma unroll
  for (int r = 0; r < 4; ++r) {
    const int row = row0 + (lane >> 4) * 4 + r;
    float vals[NT];
    float s = 0.f, s2 = 0.f;
#pragma unroll
    for (int nt = 0; nt < NT; ++nt) {
      float v = acc[nt][r] + bb[nt];
      v = 0.5f * v * (1.f + erff(v * 0.70710678118654752f));  // exact erf-gelu
      vals[nt] = v; s += v; s2 += v * v;
    }
    s  += __shfl_xor(s, 1);  s  += __shfl_xor(s, 2);  s  += __shfl_xor(s, 4);  s  += __shfl_xor(s, 8);
    s2 += __shfl_xor(s2, 1); s2 += __shfl_xor(s2, 2); s2 += __shfl_xor(s2, 4); s2 += __shfl_xor(s2, 8);
    const float mean = s * (1.f / DS);
    const float var  = s2 * (1.f / DS) - mean * mean;
    const float rstd = rsqrtf(var + 1e-12f);
#pragma unroll
    for (int nt = 0; nt < NT; ++nt) {
      float o = (vals[nt] - mean) * rstd * gg[nt] + be[nt];
      hout[(size_t)row * DS + nt * 16 + lrow] = f2bf(o);
    }
  }
}

// all four heads in one dispatch: blockIdx.y selects {P, M, A, stem}
__global__ __launch_bounds__(128, 2) void head_all_kernel(
    const unsigned short* __restrict__ x,
    const unsigned short* __restrict__ wtS, const float* __restrict__ sb,
    const float* __restrict__ sg, const float* __restrict__ sbe, unsigned short* __restrict__ hS,
    const unsigned short* __restrict__ wtP, const float* __restrict__ pb,
    const float* __restrict__ pg, const float* __restrict__ pbe, unsigned short* __restrict__ hP,
    const unsigned short* __restrict__ wtM, const float* __restrict__ mb,
    const float* __restrict__ mg, const float* __restrict__ mbe, unsigned short* __restrict__ hM,
    const unsigned short* __restrict__ wtA, const float* __restrict__ ab,
    const float* __restrict__ ag, const float* __restrict__ abe, unsigned short* __restrict__ hA) {
  if (blockIdx.y == 3)      head_body<16>(x, wtS, sb, sg, sbe, hS);
  else if (blockIdx.y == 0) head_body<8>(x, wtP, pb, pg, pbe, hP);
  else if (blockIdx.y == 1) head_body<8>(x, wtM, mb, mg, mbe, hM);
  else                      head_body<8>(x, wtA, ab, ag, abe, hA);
}

// ================= mega stats kernel: role dispatch by blockIdx.x =================
// [0,224)           : stem stats (4-deep pipelined, XCD-swizzled)
// [224,280)         : P stats   (two 256-thread groups per block)
// [280,392)         : M stats   (two col-chunks per block)
// [392,392+gaff)    : affix BCE (two col-chunks per block)
// [392+gaff, +tgtb) : target logits (one wave per token, 3 heads)

// ---- stem role ----
__device__ __forceinline__ void stem_role(
    const unsigned short* __restrict__ h, const unsigned short* __restrict__ emb,
    const float* __restrict__ bpad, float* __restrict__ psum,
    float* __restrict__ psum2, char* smem) {
  unsigned short (*lbuf)[4096] = (unsigned short(*)[4096])smem;  // 4 x 8 KB
  float* lbias = (float*)(smem + 32768);                         // 1568 floats

  const int f   = blockIdx.x;              // 0..223
  const int k2  = f >> 3;
  const int bx  = k2 % 7;                  // token group
  const int by  = (k2 / 7) * 8 + (f & 7);  // vocab chunk; 7 sharers same XCD
  const int tid  = threadIdx.x;
  const int lane = tid & 63;
  const int wave = tid >> 6;               // 0..7
  const int lrow = lane & 15;
  const int hi   = lane >> 4;
  const int lk8  = hi * 8;
  const int tok0 = bx * 512 + wave * 64;
  const int vbase0 = by * (VITERS * 16);

  // chunk bias -> LDS once (removes vmem from the K-loop: vmcnt accounting exact)
  for (int i = tid; i < VITERS * 16; i += 512) lbias[i] = bpad[vbase0 + i];

  // 64 tokens per wave, K=256, resident in registers
  bf16x8 hB[4][8];
#pragma unroll
  for (int tt = 0; tt < 4; ++tt)
#pragma unroll
    for (int ks = 0; ks < 8; ++ks)
      hB[tt][ks] = *(const bf16x8*)(h + (size_t)(tok0 + tt * 16 + lrow) * 256 + ks * 32 + lk8);

  // staging source: pre-swizzled so linear LDS dest + swizzled ds_read = identity
  const int dst16 = tid * 16;
  const int srow  = dst16 >> 9;
  const int sbyte = dst16 ^ ((srow & 7) << 4);
  const char* gs  = (const char*)emb + (size_t)vbase0 * 512 + sbyte;

  auto stage = [&](int buf, int it) {
    __builtin_amdgcn_global_load_lds(
        (const __attribute__((address_space(1))) unsigned int*)(gs + (size_t)it * 8192),
        (__attribute__((address_space(3))) unsigned int*)(&lbuf[buf][wave * 512]),
        16, 0, 0);
  };

  int loff[8];
#pragma unroll
  for (int ks = 0; ks < 8; ++ks)
    loff[ks] = (lrow * 512 + ks * 64 + hi * 16) ^ ((lrow & 7) << 4);

  float esum[4] = {0.f, 0.f, 0.f, 0.f};
  float ssum[4] = {0.f, 0.f, 0.f, 0.f};

  stage(0, 0); stage(1, 1); stage(2, 2);
  __syncthreads();   // one-time full drain: bufs 0-2 + lbias ready

#pragma unroll 1
  for (int it = 0; it < VITERS; ++it) {
    // counted wait: stage(it) complete for THIS wave; newer 2 may stay in flight
    if (it <= VITERS - 3)      asm volatile("s_waitcnt vmcnt(2)" ::: "memory");
    else if (it == VITERS - 2) asm volatile("s_waitcnt vmcnt(1)" ::: "memory");
    else                       asm volatile("s_waitcnt vmcnt(0)" ::: "memory");
    __builtin_amdgcn_s_barrier();   // all waves' stage(it) done; buf[it-1] consumed
    if (it + 3 < VITERS) stage((it + 3) & 3, it + 3);  // overwrite buf consumed at it-1

    const float4 bv = *(const float4*)(lbias + it * 16 + hi * 4);
    const char* lp = (const char*)(&lbuf[it & 3][0]);
    bf16x8 aA[8];
#pragma unroll
    for (int ks = 0; ks < 8; ++ks)
      aA[ks] = *(const bf16x8*)(lp + loff[ks]);

#pragma unroll
    for (int tt = 0; tt < 4; ++tt) {
      f32x4 acc = f32x4{0.f, 0.f, 0.f, 0.f};
#pragma unroll
      for (int ks = 0; ks < 8; ++ks)
        acc = __builtin_amdgcn_mfma_f32_16x16x32_bf16(aA[ks], hB[tt][ks], acc, 0, 0, 0);
      const float v0 = acc[0] + bv.x, v1 = acc[1] + bv.y;
      const float v2 = acc[2] + bv.z, v3 = acc[3] + bv.w;
      esum[tt] += (__expf(v0) + __expf(v1)) + (__expf(v2) + __expf(v3));
      ssum[tt] += (v0 + v1) + (v2 + v3);
    }
  }

#pragma unroll
  for (int tt = 0; tt < 4; ++tt) {
    float e = esum[tt], s = ssum[tt];
    e += __shfl_xor(e, 16); e += __shfl_xor(e, 32);
    s += __shfl_xor(s, 16); s += __shfl_xor(s, 32);
    if (hi == 0) {
      const int tok = tok0 + tt * 16 + lrow;
      psum [(size_t)tok * VCHUNK + by] = e;
      psum2[(size_t)tok * VCHUNK + by] = s;
    }
  }
}

// ---- P/M stats role (two 256-thread groups; DK = 128) ----
__device__ __forceinline__ void pm_role(
    const unsigned short* __restrict__ h, const unsigned short* __restrict__ emb,
    const float* __restrict__ bias, float* __restrict__ psum,
    float* __restrict__ psum2, int V, int NVB, int vbx, int vby, char* smem) {
  const int t256 = threadIdx.x & 255;
  const int w8   = threadIdx.x >> 6;     // 0..7 (LDS slot)
  const int grp  = threadIdx.x >> 8;     // 0..1
  const int lane = t256 & 63;
  const int wave4 = t256 >> 6;           // 0..3 within group
  const int colbase = vby * 256 + wave4 * 64;
  const int row0 = vbx * 32;
  const int lrow = lane & 15;
  const int hi   = lane >> 4;
  const int lk8  = hi * 8;
  float (*lds_e)[32] = (float(*)[32])smem;            // [8][32]
  float (*lds_s)[32] = (float(*)[32])(smem + 1024);   // [8][32]

  bf16x8 bfr[4][4];
  float bv[4];
  bool mk[4];
#pragma unroll
  for (int nt = 0; nt < 4; ++nt) {
    int col = colbase + nt * 16 + lrow;
#pragma unroll
    for (int ks = 0; ks < 4; ++ks)
      bfr[ks][nt] = *(const bf16x8*)(emb + (size_t)col * 128 + ks * 32 + lk8);
    mk[nt] = (col < V);
    bv[nt] = mk[nt] ? bias[col] : 0.f;
  }

  f32x4 acc[2][4];
#pragma unroll
  for (int rt = 0; rt < 2; ++rt)
#pragma unroll
    for (int nt = 0; nt < 4; ++nt) acc[rt][nt] = f32x4{0.f, 0.f, 0.f, 0.f};

  const unsigned short* hrow = h + (size_t)(row0 + lrow) * 128 + lk8;
#pragma unroll
  for (int ks = 0; ks < 4; ++ks) {
#pragma unroll
    for (int rt = 0; rt < 2; ++rt) {
      bf16x8 a = *(const bf16x8*)(hrow + (size_t)rt * 16 * 128 + ks * 32);
#pragma unroll
      for (int nt = 0; nt < 4; ++nt)
        acc[rt][nt] = __builtin_amdgcn_mfma_f32_16x16x32_bf16(a, bfr[ks][nt], acc[rt][nt], 0, 0, 0);
    }
  }

#pragma unroll
  for (int rt = 0; rt < 2; ++rt)
#pragma unroll
    for (int r = 0; r < 4; ++r) {
      float e = 0.f, s = 0.f;
#pragma unroll
      for (int nt = 0; nt < 4; ++nt) {
        float v = acc[rt][nt][r] + bv[nt];
        float ev = __expf(v);
        e += mk[nt] ? ev : 0.f;
        s += mk[nt] ? v : 0.f;
      }
      e += __shfl_xor(e, 1); e += __shfl_xor(e, 2); e += __shfl_xor(e, 4); e += __shfl_xor(e, 8);
      s += __shfl_xor(s, 1); s += __shfl_xor(s, 2); s += __shfl_xor(s, 4); s += __shfl_xor(s, 8);
      if (lrow == 0) {
        lds_e[w8][rt * 16 + hi * 4 + r] = e;
        lds_s[w8][rt * 16 + hi * 4 + r] = s;
      }
    }
  __syncthreads();
  if (t256 < 32) {
    const int rr = t256;
    const int b4 = grp * 4;
    float e = lds_e[b4][rr] + lds_e[b4 + 1][rr] + lds_e[b4 + 2][rr] + lds_e[b4 + 3][rr];
    float s = lds_s[b4][rr] + lds_s[b4 + 1][rr] + lds_s[b4 + 2][rr] + lds_s[b4 + 3][rr];
    const int row = row0 + rr;
    psum [(size_t)row * NVB + vby] = e;
    psum2[(size_t)row * NVB + vby] = s;
  }
}

// ---- affix BCE role (two col-chunk groups, 16 rows) ----
__device__ __forceinline__ void aff_role(
    const unsigned short* __restrict__ h, const unsigned short* __restrict__ emb,
    const float* __restrict__ bias, const int* __restrict__ asel,
    const int* __restrict__ arow, const float* __restrict__ aprob,
    float* __restrict__ partial, int Ta, int gaff, int bx, char* smem) {
  const int t256 = threadIdx.x & 255;
  const int grp  = threadIdx.x >> 8;
  const int w8   = threadIdx.x >> 6;
  const int lane = t256 & 63;
  const int wave4 = t256 >> 6;
  const int colbase = grp * 256 + wave4 * 64;
  const int lrow = lane & 15;
  const int lk8  = (lane >> 4) * 8;
  float* wred = (float*)smem;   // 8 floats

  bf16x8 bfr[4][4];
  float bv[4];
  bool mk[4];
#pragma unroll
  for (int nt = 0; nt < 4; ++nt) {
    int col = colbase + nt * 16 + lrow;
#pragma unroll
    for (int ks = 0; ks < 4; ++ks)
      bfr[ks][nt] = *(const bf16x8*)(emb + (size_t)col * DS_AFF + ks * 32 + lk8);
    mk[nt] = (col < VA);
    bv[nt] = mk[nt] ? bias[col] : 0.f;
  }

  float lsum = 0.f;
  {
    const int rb = bx * 16;
    const int ia = rb + lrow;
    const int srow = (ia < Ta) ? asel[ia] : 0;
    f32x4 acc[4];
#pragma unroll
    for (int nt = 0; nt < 4; ++nt) acc[nt] = f32x4{0.f, 0.f, 0.f, 0.f};
    const unsigned short* hrow = h + (size_t)srow * DS_AFF + lk8;
#pragma unroll
    for (int ks = 0; ks < 4; ++ks) {
      bf16x8 a = *(const bf16x8*)(hrow + ks * 32);
#pragma unroll
      for (int nt = 0; nt < 4; ++nt)
        acc[nt] = __builtin_amdgcn_mfma_f32_16x16x32_bf16(a, bfr[ks][nt], acc[nt], 0, 0, 0);
    }
#pragma unroll
    for (int r = 0; r < 4; ++r) {
      const int i2 = rb + (lane >> 4) * 4 + r;
      const bool live = (i2 < Ta);
      const int trow = live ? arow[i2] : 0;
#pragma unroll
      for (int nt = 0; nt < 4; ++nt) {
        if (live && mk[nt]) {
          float z = acc[nt][r] + bv[nt];
          float ta = aprob[(size_t)trow * VA + (colbase + nt * 16 + lrow)];
          lsum += fmaxf(z, 0.f) - z * ta + log1pf(__expf(-fabsf(z)));
        }
      }
    }
  }
#pragma unroll
  for (int m = 1; m < 64; m <<= 1) lsum += __shfl_xor(lsum, m);
  if (lane == 0) wred[w8] = lsum;
  __syncthreads();
  if (t256 == 0) {
    const int b4 = grp * 4;
    partial[grp * gaff + bx] = wred[b4] + wred[b4 + 1] + wred[b4 + 2] + wred[b4 + 3];
  }
}

// ---- target-logit role (one wave per token, all 3 heads) ----
__device__ __forceinline__ void tgt_role(
    const unsigned short* __restrict__ hS, const unsigned short* __restrict__ embS,
    const float* __restrict__ bS, const int* __restrict__ tgtS_,
    const unsigned short* __restrict__ hP, const unsigned short* __restrict__ embP,
    const float* __restrict__ bP, const int* __restrict__ tgtP_,
    const unsigned short* __restrict__ hM, const unsigned short* __restrict__ embM,
    const float* __restrict__ bM, const int* __restrict__ tgtM_,
    float* __restrict__ tlog, int T, int vb) {
  const int lane = threadIdx.x & 63;
  const int wave = threadIdx.x >> 6;
  const int t = vb * 8 + wave;
  if (t >= T) return;
  const int tg = tgtS_[t], tp = tgtP_[t], tm = tgtM_[t];
  u16x4 hv = *(const u16x4*)(hS + (size_t)t * 256 + lane * 4);
  u16x4 ev = *(const u16x4*)(embS + (size_t)tg * 256 + lane * 4);
  float d0 = bf2f(hv[0]) * bf2f(ev[0]) + bf2f(hv[1]) * bf2f(ev[1]) +
             bf2f(hv[2]) * bf2f(ev[2]) + bf2f(hv[3]) * bf2f(ev[3]);
  u16x2 hp = *(const u16x2*)(hP + (size_t)t * 128 + lane * 2);
  u16x2 ep = *(const u16x2*)(embP + (size_t)tp * 128 + lane * 2);
  float d1 = bf2f(hp[0]) * bf2f(ep[0]) + bf2f(hp[1]) * bf2f(ep[1]);
  u16x2 hm = *(const u16x2*)(hM + (size_t)t * 128 + lane * 2);
  u16x2 em = *(const u16x2*)(embM + (size_t)tm * 128 + lane * 2);
  float d2 = bf2f(hm[0]) * bf2f(em[0]) + bf2f(hm[1]) * bf2f(em[1]);
#pragma unroll
  for (int m = 1; m < 64; m <<= 1) {
    d0 += __shfl_xor(d0, m); d1 += __shfl_xor(d1, m); d2 += __shfl_xor(d2, m);
  }
  if (lane == 0) {
    tlog[t]            = d0 + bS[tg];
    tlog[TPAD + t]     = d1 + bP[tp];
    tlog[2 * TPAD + t] = d2 + bM[tm];
  }
}

__global__ __launch_bounds__(512, 2) void mega_stats_kernel(
    const unsigned short* __restrict__ hS, const unsigned short* __restrict__ embS,
    const float* __restrict__ bpadS, float* __restrict__ psS, float* __restrict__ ps2S,
    const unsigned short* __restrict__ hP, const unsigned short* __restrict__ embP,
    const float* __restrict__ p_bias, float* __restrict__ psP, float* __restrict__ ps2P,
    const unsigned short* __restrict__ hM, const unsigned short* __restrict__ embM,
    const float* __restrict__ m_bias, float* __restrict__ psM, float* __restrict__ ps2M,
    const unsigned short* __restrict__ hA, const unsigned short* __restrict__ embA,
    const float* __restrict__ a_bias, const int* __restrict__ asel,
    const int* __restrict__ arow, const float* __restrict__ aprob,
    float* __restrict__ affp,
    const float* __restrict__ s_bias, const int* __restrict__ tgtS,
    const int* __restrict__ tgtP, const int* __restrict__ tgtM,
    float* __restrict__ tlog, int T, int Ta, int gaff) {
  __shared__ alignas(16) char smem_[39040];  // stem: 32KB tiles + 6.1KB bias; others reuse
  const int bid = blockIdx.x;
  if (bid < 224) {
    stem_role(hS, embS, bpadS, psS, ps2S, smem_);
  } else if (bid < 280) {
    pm_role(hP, embP, p_bias, psP, ps2P, VP, NVB_P,
            (bid - 224) * 2 + (threadIdx.x >> 8), 0, smem_);
  } else if (bid < 392) {
    pm_role(hM, embM, m_bias, psM, ps2M, VM, NVB_M,
            bid - 280, threadIdx.x >> 8, smem_);
  } else if (bid < 392 + gaff) {
    aff_role(hA, embA, a_bias, asel, arow, aprob, affp, Ta, gaff, bid - 392, smem_);
  } else {
    tgt_role(hS, embS, s_bias, tgtS, hP, embP, p_bias, tgtP,
             hM, embM, m_bias, tgtM, tlog, T, bid - 392 - gaff);
  }
}

// ---------------- per-row combine ----------------
__global__ __launch_bounds__(256) void combine2_kernel(
    const float* __restrict__ psS, const float* __restrict__ ps2S,
    const float* __restrict__ psP, const float* __restrict__ ps2P,
    const float* __restrict__ psM, const float* __restrict__ ps2M,
    const float* __restrict__ tlog,
    float* __restrict__ nll, float* __restrict__ sm, int T) {
  const int lane = threadIdx.x & 63;
  const int wave = threadIdx.x >> 6;
  const int t = blockIdx.x * 4 + wave;
  if (t >= T) return;

  float z = 0.f, s = 0.f;
  if (lane < VCHUNK) {
    z = psS[(size_t)t * VCHUNK + lane];
    s = ps2S[(size_t)t * VCHUNK + lane];
  }
#pragma unroll
  for (int m = 1; m < 64; m <<= 1) { z += __shfl_xor(z, m); s += __shfl_xor(s, m); }
  if (lane == 0) {
    z -= PAD_E;  // pad vocab rows contributed exp(0)=1 each
    float lz = logf(z);
    nll[t] = lz - tlog[t];
    sm[t]  = (float)VS * lz - s;

    float zP = psP[t], sP = ps2P[t];
    float lzP = logf(zP);
    nll[TPAD + t] = lzP - tlog[TPAD + t];
    sm[TPAD + t]  = (float)VP * lzP - sP;

    float zM = psM[2 * t] + psM[2 * t + 1];
    float sM = ps2M[2 * t] + ps2M[2 * t + 1];
    float lzM = logf(zM);
    nll[2 * TPAD + t] = lzM - tlog[2 * TPAD + t];
    sm[2 * TPAD + t]  = (float)VM * lzM - sM;
  }
}

// ---------------- finalize ----------------
__global__ __launch_bounds__(256) void finalize_kernel(
    const float* __restrict__ nll, const float* __restrict__ sm,
    const float* __restrict__ affp, int naff, float* __restrict__ out, int T, int Ta) {
  __shared__ float red[256];
  const int tid = threadIdx.x;
  float nll_m[3], sm_m[3];
  for (int h2 = 0; h2 < 3; ++h2) {
    float a = 0.f, b = 0.f;
    for (int t = tid; t < T; t += 256) { a += nll[h2 * TPAD + t]; b += sm[h2 * TPAD + t]; }
    red[tid] = a; __syncthreads();
    for (int s = 128; s > 0; s >>= 1) { if (tid < s) red[tid] += red[tid + s]; __syncthreads(); }
    float asum = red[0]; __syncthreads();
    red[tid] = b; __syncthreads();
    for (int s = 128; s > 0; s >>= 1) { if (tid < s) red[tid] += red[tid + s]; __syncthreads(); }
    float bsm = red[0]; __syncthreads();
    nll_m[h2] = asum / (float)T;
    sm_m[h2]  = bsm / (float)T;
  }
  float av = 0.f;
  for (int i = tid; i < naff; i += 256) av += affp[i];
  red[tid] = av; __syncthreads();
  for (int s = 128; s > 0; s >>= 1) { if (tid < s) red[tid] += red[tid + s]; __syncthreads(); }
  if (tid == 0) {
    const float Vv[3] = {(float)VS, (float)VP, (float)VM};
    for (int h2 = 0; h2 < 3; ++h2) {
      float eps_i = 0.1f / (Vv[h2] - 1.f);
      out[h2] = (1.0f - 0.1f - eps_i) * nll_m[h2] + eps_i * sm_m[h2];
      out[4 + h2] = nll_m[h2];
    }
    out[3] = red[0] / ((float)Ta * (float)VA);
  }
}

// ---------------- host launcher ----------------
extern "C" void kernel_launch(void* const* d_in, const int* in_sizes, int n_in,
                              void* d_out, int out_size, void* d_ws, size_t ws_size,
                              hipStream_t stream) {
  const float* tr      = (const float*)d_in[0];
  const float* aprob   = (const float*)d_in[1];
  const int* stems     = (const int*)d_in[2];
  const int* postags   = (const int*)d_in[3];
  const int* morphs    = (const int*)d_in[4];
  const int* hsel      = (const int*)d_in[5];
  const int* tsel      = (const int*)d_in[6];
  const int* asel      = (const int*)d_in[7];
  const float* s_emb = (const float*)d_in[8],  *s_W = (const float*)d_in[9];
  const float* s_b   = (const float*)d_in[10], *s_g = (const float*)d_in[11];
  const float* s_be  = (const float*)d_in[12], *s_bias = (const float*)d_in[13];
  const float* p_emb = (const float*)d_in[14], *p_W = (const float*)d_in[15];
  const float* p_b   = (const float*)d_in[16], *p_g = (const float*)d_in[17];
  const float* p_be  = (const float*)d_in[18], *p_bias = (const float*)d_in[19];
  const float* m_emb = (const float*)d_in[20], *m_W = (const float*)d_in[21];
  const float* m_b   = (const float*)d_in[22], *m_g = (const float*)d_in[23];
  const float* m_be  = (const float*)d_in[24], *m_bias = (const float*)d_in[25];
  const float* a_emb = (const float*)d_in[26], *a_W = (const float*)d_in[27];
  const float* a_b   = (const float*)d_in[28], *a_g = (const float*)d_in[29];
  const float* a_be  = (const float*)d_in[30], *a_bias = (const float*)d_in[31];

  const int T  = in_sizes[5];   // 3576
  const int Ta = in_sizes[7];   // ~2682

  size_t off = 0;
  auto alloc = [&](size_t nbytes) -> char* {
    char* p = (char*)d_ws + off;
    off = (off + nbytes + 255) & ~(size_t)255;
    return p;
  };
  unsigned short* x    = (unsigned short*)alloc((size_t)TPAD * D_MODEL * 2);
  unsigned short* wtS  = (unsigned short*)alloc((size_t)DS_STEM * D_MODEL * 2);
  unsigned short* wtP  = (unsigned short*)alloc((size_t)DS_POS * D_MODEL * 2);
  unsigned short* wtM  = (unsigned short*)alloc((size_t)DS_MORPH * D_MODEL * 2);
  unsigned short* wtA  = (unsigned short*)alloc((size_t)DS_AFF * D_MODEL * 2);
  unsigned short* embS = (unsigned short*)alloc((size_t)VS_PAD * DS_STEM * 2);
  unsigned short* embP = (unsigned short*)alloc((size_t)256 * DS_POS * 2);
  unsigned short* embM = (unsigned short*)alloc((size_t)512 * DS_MORPH * 2);
  unsigned short* embA = (unsigned short*)alloc((size_t)512 * DS_AFF * 2);
  unsigned short* hS   = (unsigned short*)alloc((size_t)TPAD * DS_STEM * 2);
  unsigned short* hP   = (unsigned short*)alloc((size_t)TPAD * DS_POS * 2);
  unsigned short* hM   = (unsigned short*)alloc((size_t)TPAD * DS_MORPH * 2);
  unsigned short* hA   = (unsigned short*)alloc((size_t)TPAD * DS_AFF * 2);
  float* bpadS = (float*)alloc((size_t)VS_PAD * 4);
  float* psS   = (float*)alloc((size_t)TPAD * VCHUNK * 4);
  float* ps2S  = (float*)alloc((size_t)TPAD * VCHUNK * 4);
  float* psP   = (float*)alloc((size_t)TPAD * NVB_P * 4);
  float* ps2P  = (float*)alloc((size_t)TPAD * NVB_P * 4);
  float* psM   = (float*)alloc((size_t)TPAD * NVB_M * 4);
  float* ps2M  = (float*)alloc((size_t)TPAD * NVB_M * 4);
  float* tlog  = (float*)alloc((size_t)3 * TPAD * 4);
  int*   tgtS  = (int*)alloc((size_t)TPAD * 4);
  int*   tgtP  = (int*)alloc((size_t)TPAD * 4);
  int*   tgtM  = (int*)alloc((size_t)TPAD * 4);
  int*   arow  = (int*)alloc((size_t)TPAD * 4);
  float* nllb  = (float*)alloc((size_t)3 * TPAD * 4);
  float* smb   = (float*)alloc((size_t)3 * TPAD * 4);
  float* affp  = (float*)alloc(2048);
  (void)ws_size; (void)n_in; (void)out_size;

  const int gaff = (Ta + 15) / 16;
  const int tgtb = (T + 7) / 8;

  // 1. gather + cast predictor states, pre-gather targets & affix rows
  gather_x_kernel<<<(TPAD * D_MODEL) / 256, 256, 0, stream>>>(
      tr, hsel, tsel, asel, stems, postags, morphs, x, tgtS, tgtP, tgtM, arow, T, Ta);
  // 2. fused W transposes -> [DS, 768] bf16
  transpose_all_kernel<<<491520 / 256, 256, 0, stream>>>(s_W, p_W, m_W, a_W, wtS, wtP, wtM, wtA);
  // 3. fused emb -> bf16 casts + padded stem bias
  conv_emb_all_kernel<<<12753, 256, 0, stream>>>(
      s_emb, p_emb, m_emb, a_emb, s_bias, embS, embP, embM, embA, bpadS);
  // 4. all head transforms in one dispatch
  head_all_kernel<<<dim3(TPAD / 32, 4), 128, 0, stream>>>(
      x, wtS, s_b, s_g, s_be, hS, wtP, p_b, p_g, p_be, hP,
      wtM, m_b, m_g, m_be, hM, wtA, a_b, a_g, a_be, hA);
  // 5. mega: stem stats (4-deep pipeline) + P/M stats + affix BCE + target logits
  mega_stats_kernel<<<392 + gaff + tgtb, 512, 0, stream>>>(
      hS, embS, bpadS, psS, ps2S,
      hP, embP, p_bias, psP, ps2P,
      hM, embM, m_bias, psM, ps2M,
      hA, embA, a_bias, asel, arow, aprob, affp,
      s_bias, tgtS, tgtP, tgtM, tlog, T, Ta, gaff);
  // 6. per-row combine + final reduction
  combine2_kernel<<<(T + 3) / 4, 256, 0, stream>>>(psS, ps2S, psP, ps2P, psM, ps2M, tlog, nllb, smb, T);
  finalize_kernel<<<1, 256, 0, stream>>>(nllb, smb, affp, gaff * 2, (float*)d_out, T, Ta);
}